// Round 3
// baseline (353.183 us; speedup 1.0000x reference)
//
#include <hip/hip_runtime.h>
#include <hip/hip_bf16.h>

typedef __hip_bfloat16 bf16;

#define B_      16
#define N_      1024
#define NHEADS_ 4
#define ALPHA_  0.2f

__device__ __forceinline__ float b2f(bf16 v) { return __bfloat162float(v); }
__device__ __forceinline__ float lrelu(float s) { return s > 0.f ? s : ALPHA_ * s; }
__device__ __forceinline__ float eluf(float u) { return u > 0.f ? u : __expf(u) - 1.f; }

template <bool F32>
__device__ __forceinline__ float ldin(const void* p, size_t i) {
    if constexpr (F32) return ((const float*)p)[i];
    else               return b2f(((const bf16*)p)[i]);
}

// ---------------------------------------------------------------------------
// Input dtype detector: interpret first 4096 elems of x as bf16. If the buffer
// is really fp32, even elements are fp32 low-halves -> ~88% decode to |v|>1e3,
// |v|<1e-6, or NaN/inf. Genuine bf16 N(0,1) data has ~0 such outliers.
// flag=1 -> inputs are fp32.  (Round-1/2 evidence: inputs ARE fp32.)
__global__ void detect_kernel(const void* __restrict__ x, int* __restrict__ flag)
{
    __shared__ int cnt;
    if (threadIdx.x == 0) cnt = 0;
    __syncthreads();
    int c = 0;
    for (int i = threadIdx.x; i < 4096; i += 256) {
        float v = b2f(((const bf16*)x)[i]);
        float av = fabsf(v);
        if (!(av <= 1e3f) || (v != 0.f && av < 1e-6f)) c++;  // !(<=) catches NaN
    }
    atomicAdd(&cnt, c);
    __syncthreads();
    if (threadIdx.x == 0) *flag = (cnt > 256) ? 1 : 0;
}

// ---------------------------------------------------------------------------
// proj1: h1[head][b][n][64] = x[b][n][:64] @ (n<512 ? W1[head] : W2[head])
//        A1/A2[head][b][n]  = h1 . a[head][:64] / a[head][64:]
template <bool F32>
__device__ __forceinline__ void proj1_body(
    const void* __restrict__ x, const void* __restrict__ W1,
    const void* __restrict__ W2, const void* __restrict__ av,
    float* __restrict__ h1, float* __restrict__ A1, float* __restrict__ A2)
{
    const int tile = blockIdx.x, b = blockIdx.y, head = blockIdx.z;
    const int n0 = tile * 64;
    const void* W = (n0 < 512) ? W1 : W2;
    const size_t Woff = (size_t)head * 64 * 64;
    const size_t aoff = (size_t)head * 128;

    __shared__ float xs[64][65];   // +1 pad: conflict-free row reads
    __shared__ float Wl[64][64];
    __shared__ float as_[128];

    const int tid = threadIdx.x;
    for (int i = 0; i < 16; ++i) {
        int idx = i * 256 + tid;
        int r = idx >> 6, f = idx & 63;
        xs[r][f] = ldin<F32>(x, (size_t)(b * N_ + n0 + r) * 64 + f);
        Wl[r][f] = ldin<F32>(W, Woff + idx);     // Wl[f][c] layout (same flat order)
    }
    if (tid < 128) as_[tid] = ldin<F32>(av, aoff + tid);
    __syncthreads();

    const int r = tid >> 2, c0 = (tid & 3) * 16;   // 4 threads per row
    float acc[16];
#pragma unroll
    for (int j = 0; j < 16; ++j) acc[j] = 0.f;
#pragma unroll 8
    for (int f = 0; f < 64; ++f) {
        float xv = xs[r][f];
#pragma unroll
        for (int j = 0; j < 16; ++j) acc[j] += xv * Wl[f][c0 + j];
    }

    float* hrow = h1 + ((size_t)((head * B_ + b) * N_ + n0 + r)) * 64 + c0;
#pragma unroll
    for (int j = 0; j < 16; j += 4)
        *(float4*)(hrow + j) = make_float4(acc[j], acc[j+1], acc[j+2], acc[j+3]);

    float p1 = 0.f, p2 = 0.f;
#pragma unroll
    for (int j = 0; j < 16; ++j) {
        p1 += acc[j] * as_[c0 + j];
        p2 += acc[j] * as_[64 + c0 + j];
    }
    p1 += __shfl_xor(p1, 1); p1 += __shfl_xor(p1, 2);
    p2 += __shfl_xor(p2, 1); p2 += __shfl_xor(p2, 2);
    if ((tid & 3) == 0) {
        A1[(head * B_ + b) * N_ + n0 + r] = p1;
        A2[(head * B_ + b) * N_ + n0 + r] = p2;
    }
}

__global__ __launch_bounds__(256) void proj1_kernel(
    const void* x, const void* W1, const void* W2, const void* av,
    const int* __restrict__ flagp,
    float* h1, float* A1, float* A2)
{
    if (*flagp) proj1_body<true >(x, W1, W2, av, h1, A1, A2);
    else        proj1_body<false>(x, W1, W2, av, h1, A1, A2);
}

// ---------------------------------------------------------------------------
// proj2: h2[b][n][64] = xc[b][n][:256] @ (n<512 ? W1o : W2o); A1o/A2o dots
template <bool F32>
__device__ __forceinline__ void proj2_body(
    const float* __restrict__ xc, const void* __restrict__ W1o,
    const void* __restrict__ W2o, const void* __restrict__ ao,
    float* __restrict__ h2, float* __restrict__ A1o, float* __restrict__ A2o)
{
    const int tile = blockIdx.x, b = blockIdx.y;
    const int n0 = tile * 64;
    const void* W = (n0 < 512) ? W1o : W2o;

    __shared__ float xs[64][65];
    __shared__ float Wl[64][64];
    __shared__ float as_[128];

    const int tid = threadIdx.x;
    if (tid < 128) as_[tid] = ldin<F32>(ao, tid);

    const int r = tid >> 2, c0 = (tid & 3) * 16;
    float acc[16];
#pragma unroll
    for (int j = 0; j < 16; ++j) acc[j] = 0.f;

    for (int kc = 0; kc < 4; ++kc) {
        __syncthreads();
        for (int i = 0; i < 16; ++i) {
            int idx = i * 256 + tid;
            int rr = idx >> 6, f = idx & 63;
            xs[rr][f] = xc[((size_t)(b * N_ + n0 + rr)) * 256 + kc * 64 + f];
            Wl[rr][f] = ldin<F32>(W, (size_t)(kc * 64 + rr) * 64 + f);
        }
        __syncthreads();
#pragma unroll 8
        for (int f = 0; f < 64; ++f) {
            float xv = xs[r][f];
#pragma unroll
            for (int j = 0; j < 16; ++j) acc[j] += xv * Wl[f][c0 + j];
        }
    }

    float* hrow = h2 + ((size_t)(b * N_ + n0 + r)) * 64 + c0;
#pragma unroll
    for (int j = 0; j < 16; j += 4)
        *(float4*)(hrow + j) = make_float4(acc[j], acc[j+1], acc[j+2], acc[j+3]);

    float p1 = 0.f, p2 = 0.f;
#pragma unroll
    for (int j = 0; j < 16; ++j) {
        p1 += acc[j] * as_[c0 + j];
        p2 += acc[j] * as_[64 + c0 + j];
    }
    p1 += __shfl_xor(p1, 1); p1 += __shfl_xor(p1, 2);
    p2 += __shfl_xor(p2, 1); p2 += __shfl_xor(p2, 2);
    if ((tid & 3) == 0) {
        A1o[b * N_ + n0 + r] = p1;
        A2o[b * N_ + n0 + r] = p2;
    }
}

__global__ __launch_bounds__(256) void proj2_kernel(
    const float* xc, const void* W1o, const void* W2o, const void* ao,
    const int* __restrict__ flagp,
    float* h2, float* A1o, float* A2o)
{
    if (*flagp) proj2_body<true >(xc, W1o, W2o, ao, h2, A1o, A2o);
    else        proj2_body<false>(xc, W1o, W2o, ao, h2, A1o, A2o);
}

// ---------------------------------------------------------------------------
// Fused attention: for 64 rows n, t[m]=exp(mask[n,m]*lrelu(A1[n]+A2[m])),
// Z=sum_m t, agg[d]=sum_m t[m]*H[m][d]; write elu(agg/Z) (fp32 xc or fp32 out)
// and optionally attn rows t/Z (fp32). Z accumulated redundantly per-thread.
template <bool F32>
__device__ __forceinline__ void attn_body(
    const float* __restrict__ A1g, const float* __restrict__ A2g,
    const float* __restrict__ Hg, const void* __restrict__ maskg,
    float* __restrict__ xc_out,      // layer 1: [b][n][head*64+d], else null
    float* __restrict__ out_f,       // layer 2: [b][n][d], else null
    float* __restrict__ attn_f)      // layer 2: [b][n][m], else null
{
    const int tile = blockIdx.x, b = blockIdx.y, head = blockIdx.z;
    const int n0 = tile * 64;
    const size_t bh = (size_t)head * B_ + b;
    const float* A1 = A1g + bh * N_;
    const float* A2 = A2g + bh * N_;
    const float* H  = Hg + bh * N_ * 64;

    __shared__ float hs[64][64];     // H tile [m][d]
    __shared__ float ts[64][68];     // t tile [m][row]; stride 68 keeps 16B align
    __shared__ float A1s[64];
    __shared__ float invz[64];

    const int tid = threadIdx.x;
    if (tid < 64) A1s[tid] = A1[n0 + tid];

    const int rg = tid >> 4, dg = tid & 15;
    const int r0 = rg * 4, d0 = dg * 4;
    float acc[4][4] = {};
    float z4[4] = {0.f, 0.f, 0.f, 0.f};

    for (int mt = 0; mt < 16; ++mt) {
        const int m0 = mt * 64;
        __syncthreads();   // prev-tile reads done (also orders A1s on mt=0)
        for (int i = 0; i < 4; ++i) {
            int idx = i * 256 + tid;
            int mr = idx >> 4, dc = (idx & 15) * 4;
            *(float4*)&hs[mr][dc] = *(const float4*)&H[(size_t)(m0 + mr) * 64 + dc];
        }
        for (int i = 0; i < 16; ++i) {
            int idx = i * 256 + tid;
            int rr = idx >> 6, mc = idx & 63;
            float s = A1s[rr] + A2[m0 + mc];
            float mv = ldin<F32>(maskg, (size_t)(n0 + rr) * N_ + m0 + mc);
            ts[mc][rr] = __expf(mv * lrelu(s));
        }
        __syncthreads();
#pragma unroll 4
        for (int m = 0; m < 64; ++m) {
            float4 t4 = *(float4*)&ts[m][r0];
            float4 h4 = *(float4*)&hs[m][d0];
            z4[0] += t4.x; z4[1] += t4.y; z4[2] += t4.z; z4[3] += t4.w;
            acc[0][0] += t4.x * h4.x; acc[0][1] += t4.x * h4.y; acc[0][2] += t4.x * h4.z; acc[0][3] += t4.x * h4.w;
            acc[1][0] += t4.y * h4.x; acc[1][1] += t4.y * h4.y; acc[1][2] += t4.y * h4.z; acc[1][3] += t4.y * h4.w;
            acc[2][0] += t4.z * h4.x; acc[2][1] += t4.z * h4.y; acc[2][2] += t4.z * h4.z; acc[2][3] += t4.z * h4.w;
            acc[3][0] += t4.w * h4.x; acc[3][1] += t4.w * h4.y; acc[3][2] += t4.w * h4.z; acc[3][3] += t4.w * h4.w;
        }
    }

    if (xc_out) {
#pragma unroll
        for (int i = 0; i < 4; ++i) {
            float inv = 1.f / z4[i];
            float* dst = xc_out + ((size_t)(b * N_ + n0 + r0 + i)) * 256 + head * 64 + d0;
            *(float4*)dst = make_float4(eluf(acc[i][0] * inv), eluf(acc[i][1] * inv),
                                        eluf(acc[i][2] * inv), eluf(acc[i][3] * inv));
        }
    }
    if (out_f) {
#pragma unroll
        for (int i = 0; i < 4; ++i) {
            float inv = 1.f / z4[i];
            float* dst = out_f + ((size_t)(b * N_ + n0 + r0 + i)) * 64 + d0;
            *(float4*)dst = make_float4(eluf(acc[i][0] * inv), eluf(acc[i][1] * inv),
                                        eluf(acc[i][2] * inv), eluf(acc[i][3] * inv));
        }
        if (dg == 0) {
#pragma unroll
            for (int i = 0; i < 4; ++i) invz[r0 + i] = 1.f / z4[i];
        }
        __syncthreads();
        // recompute t rows * invz -> attn output (coalesced fp32 stores)
        for (int i = 0; i < 256; ++i) {
            int idx = i * 256 + tid;
            int rr = idx >> 10, m = idx & 1023;
            float s = A1s[rr] + A2[m];
            float mv = ldin<F32>(maskg, (size_t)(n0 + rr) * N_ + m);
            attn_f[((size_t)(b * N_ + n0 + rr)) * N_ + m] = __expf(mv * lrelu(s)) * invz[rr];
        }
    }
}

__global__ __launch_bounds__(256) void attn_kernel(
    const float* A1g, const float* A2g, const float* Hg, const void* maskg,
    const int* __restrict__ flagp,
    float* xc_out, float* out_f, float* attn_f)
{
    if (*flagp) attn_body<true >(A1g, A2g, Hg, maskg, xc_out, out_f, attn_f);
    else        attn_body<false>(A1g, A2g, Hg, maskg, xc_out, out_f, attn_f);
}

// ---------------------------------------------------------------------------
extern "C" void kernel_launch(void* const* d_in, const int* in_sizes, int n_in,
                              void* d_out, int out_size, void* d_ws, size_t ws_size,
                              hipStream_t stream)
{
    const void* x    = d_in[0];
    const void* mask = d_in[1];
    const void* W1   = d_in[2];
    const void* W2   = d_in[3];
    const void* a    = d_in[4];
    const void* W1o  = d_in[5];
    const void* W2o  = d_in[6];
    const void* ao   = d_in[7];

    float* out      = (float*)d_out;                 // [16,1024,64] fp32
    float* attn_out = out + (size_t)B_ * N_ * 64;    // [16,1024,1024] fp32

    // ws layout (floats), total ~9.6M floats ~= 38.4 MB
    float* ws  = (float*)d_ws;
    float* h1  = ws;                 // 4*16*1024*64 = 4194304
    float* A1  = h1 + 4194304;       // 65536
    float* A2  = A1 + 65536;         // 65536
    float* xc  = A2 + 65536;         // 16*1024*256 = 4194304
    float* h2  = xc + 4194304;       // 16*1024*64 = 1048576
    float* A1o = h2 + 1048576;       // 16384
    float* A2o = A1o + 16384;        // 16384
    int*   dfl = (int*)(A2o + 16384);

    detect_kernel<<<1, 256, 0, stream>>>(x, dfl);
    proj1_kernel<<<dim3(16, 16, 4), 256, 0, stream>>>(x, W1, W2, a, dfl, h1, A1, A2);
    attn_kernel <<<dim3(16, 16, 4), 256, 0, stream>>>(A1, A2, h1, mask, dfl, xc, nullptr, nullptr);
    proj2_kernel<<<dim3(16, 16, 1), 256, 0, stream>>>(xc, W1o, W2o, ao, dfl, h2, A1o, A2o);
    attn_kernel <<<dim3(16, 16, 1), 256, 0, stream>>>(A1o, A2o, h2, mask, dfl, nullptr, out, attn_out);
}

// Round 4
// 252.647 us; speedup vs baseline: 1.3979x; 1.3979x over previous
//
#include <hip/hip_runtime.h>
#include <hip/hip_bf16.h>

#define B_      16
#define N_      1024
#define ALPHA_  0.2f

typedef __attribute__((ext_vector_type(8))) __bf16 bf16x8;
typedef __attribute__((ext_vector_type(4))) float  floatx4;

__device__ __forceinline__ float lrelu(float s) { return s > 0.f ? s : ALPHA_ * s; }
__device__ __forceinline__ float eluf(float u)  { return u > 0.f ? u : __expf(u) - 1.f; }

__device__ __forceinline__ floatx4 mfma_bf16(bf16x8 a, bf16x8 b, floatx4 c) {
    return __builtin_amdgcn_mfma_f32_16x16x32_bf16(a, b, c, 0, 0, 0);
}

// ---------------------------------------------------------------------------
// proj1: h = x[b,n0:n0+64,:64] @ (n0<512 ? W1[head] : W2[head])   (fp32 math)
// writes h1t[(head*16+b)*64 + d][m] (bf16, transposed) + A1/A2 fp32.
__global__ __launch_bounds__(256) void proj1_kernel(
    const float* __restrict__ x, const float* __restrict__ W1,
    const float* __restrict__ W2, const float* __restrict__ av,
    __bf16* __restrict__ h1t, float* __restrict__ A1, float* __restrict__ A2)
{
    const int tile = blockIdx.x, b = blockIdx.y, head = blockIdx.z;
    const int n0 = tile * 64;
    const float* W  = ((n0 < 512) ? W1 : W2) + head * 64 * 64;
    const float* ah = av + head * 128;

    __shared__ float xs[64][65];   // +1 pad: conflict-free column reads
    __shared__ float Wl[64][64];
    __shared__ float as_[128];

    const int tid = threadIdx.x;
    for (int i = 0; i < 16; ++i) {
        int idx = i * 256 + tid;
        int r = idx >> 6, f = idx & 63;
        xs[r][f] = x[(size_t)(b * N_ + n0 + r) * 64 + f];
        Wl[r][f] = W[idx];                       // Wl[f][c]
    }
    if (tid < 128) as_[tid] = ah[tid];
    __syncthreads();

    const int r = tid >> 2, c0 = (tid & 3) * 16;
    float acc[16];
#pragma unroll
    for (int j = 0; j < 16; ++j) acc[j] = 0.f;
#pragma unroll 8
    for (int f = 0; f < 64; ++f) {
        float xv = xs[r][f];
#pragma unroll
        for (int j = 0; j < 16; ++j) acc[j] += xv * Wl[f][c0 + j];
    }

    float p1 = 0.f, p2 = 0.f;
#pragma unroll
    for (int j = 0; j < 16; ++j) {
        p1 += acc[j] * as_[c0 + j];
        p2 += acc[j] * as_[64 + c0 + j];
    }
    p1 += __shfl_xor(p1, 1); p1 += __shfl_xor(p1, 2);
    p2 += __shfl_xor(p2, 1); p2 += __shfl_xor(p2, 2);
    const int bh = head * B_ + b;
    if ((tid & 3) == 0) {
        A1[bh * N_ + n0 + r] = p1;
        A2[bh * N_ + n0 + r] = p2;
    }

    // bounce h through xs (overwrite) -> transposed bf16 global
    __syncthreads();
#pragma unroll
    for (int j = 0; j < 16; ++j) xs[r][c0 + j] = acc[j];
    __syncthreads();
    const int d = tid & 63, ch = tid >> 6;
    bf16x8 p0, p1v;
#pragma unroll
    for (int j = 0; j < 8; ++j) p0[j]  = (__bf16)xs[ch * 16 + j][d];
#pragma unroll
    for (int j = 0; j < 8; ++j) p1v[j] = (__bf16)xs[ch * 16 + 8 + j][d];
    bf16x8* dst = (bf16x8*)(h1t + ((size_t)bh * 64 + d) * N_ + n0 + ch * 16);
    dst[0] = p0; dst[1] = p1v;
}

// ---------------------------------------------------------------------------
// proj2: h2 = xc[b,n0:n0+64,:256] @ (n0<512 ? W1o : W2o); writes h2t bf16 + A dots
__global__ __launch_bounds__(256) void proj2_kernel(
    const float* __restrict__ xc, const float* __restrict__ W1o,
    const float* __restrict__ W2o, const float* __restrict__ ao,
    __bf16* __restrict__ h2t, float* __restrict__ A1o, float* __restrict__ A2o)
{
    const int tile = blockIdx.x, b = blockIdx.y;
    const int n0 = tile * 64;
    const float* W = (n0 < 512) ? W1o : W2o;

    __shared__ float xs[64][65];
    __shared__ float Wl[64][64];
    __shared__ float as_[128];

    const int tid = threadIdx.x;
    if (tid < 128) as_[tid] = ao[tid];

    const int r = tid >> 2, c0 = (tid & 3) * 16;
    float acc[16];
#pragma unroll
    for (int j = 0; j < 16; ++j) acc[j] = 0.f;

    for (int kc = 0; kc < 4; ++kc) {
        __syncthreads();
        for (int i = 0; i < 16; ++i) {
            int idx = i * 256 + tid;
            int rr = idx >> 6, f = idx & 63;
            xs[rr][f] = xc[((size_t)(b * N_ + n0 + rr)) * 256 + kc * 64 + f];
            Wl[rr][f] = W[(size_t)(kc * 64 + rr) * 64 + f];
        }
        __syncthreads();
#pragma unroll 8
        for (int f = 0; f < 64; ++f) {
            float xv = xs[r][f];
#pragma unroll
            for (int j = 0; j < 16; ++j) acc[j] += xv * Wl[f][c0 + j];
        }
    }

    float p1 = 0.f, p2 = 0.f;
#pragma unroll
    for (int j = 0; j < 16; ++j) {
        p1 += acc[j] * as_[c0 + j];
        p2 += acc[j] * as_[64 + c0 + j];
    }
    p1 += __shfl_xor(p1, 1); p1 += __shfl_xor(p1, 2);
    p2 += __shfl_xor(p2, 1); p2 += __shfl_xor(p2, 2);
    if ((tid & 3) == 0) {
        A1o[b * N_ + n0 + r] = p1;
        A2o[b * N_ + n0 + r] = p2;
    }

    __syncthreads();
#pragma unroll
    for (int j = 0; j < 16; ++j) xs[r][c0 + j] = acc[j];
    __syncthreads();
    const int d = tid & 63, ch = tid >> 6;
    bf16x8 p0, p1v;
#pragma unroll
    for (int j = 0; j < 8; ++j) p0[j]  = (__bf16)xs[ch * 16 + j][d];
#pragma unroll
    for (int j = 0; j < 8; ++j) p1v[j] = (__bf16)xs[ch * 16 + 8 + j][d];
    bf16x8* dst = (bf16x8*)(h2t + ((size_t)b * 64 + d) * N_ + n0 + ch * 16);
    dst[0] = p0; dst[1] = p1v;
}

// ---------------------------------------------------------------------------
// MFMA attention. Per block: 64 rows n, all 64 d. K-loop over m in 64-chunks:
// t[n][m]=exp(mask*lrelu(A1[n]+A2[m])) -> bf16 LDS (A operand);
// Ht[d][m] bf16 staged from global (B operand); O += t . H via 16x16x32 MFMA.
// Z accumulated in fp32 by staging threads (disjoint m-quarters), 2-shfl reduce.
__global__ __launch_bounds__(256) void attn_mfma_kernel(
    const float* __restrict__ A1g, const float* __restrict__ A2g,
    const __bf16* __restrict__ Htg, const float* __restrict__ maskg,
    float* __restrict__ xc_out,      // layer 1: [b][n][head*64+d], else null
    float* __restrict__ out_f,       // layer 2: [b][n][d], else null
    float* __restrict__ attn_f)      // layer 2: [b][n][m], else null
{
    const int tile = blockIdx.x, b = blockIdx.y, head = blockIdx.z;
    const int n0 = tile * 64;
    const int bh = head * B_ + b;    // layer 2: head=0 -> bh=b
    const float* A1 = A1g + (size_t)bh * N_;
    const float* A2 = A2g + (size_t)bh * N_;
    const __bf16* Ht_glob = Htg + (size_t)bh * 64 * N_;

    __shared__ __bf16 ts[64][72];    // t tile [n][m], +8 pad (16B-aligned rows)
    __shared__ __bf16 Ht[64][72];    // H^T tile [d][m]
    __shared__ float A1s[64];
    __shared__ float invz[64];

    const int tid = threadIdx.x;
    if (tid < 64) A1s[tid] = A1[n0 + tid];

    const int r = tid >> 2, q = tid & 3;           // staging: row r, m-quarter q
    const float a1r = A1[n0 + r];
    const int w = tid >> 6, L = tid & 63;          // MFMA: wave w, lane L
    const int quad = L >> 4, lo = L & 15;

    floatx4 acc[4] = {{0,0,0,0},{0,0,0,0},{0,0,0,0},{0,0,0,0}};
    float zacc = 0.f;

    for (int mt = 0; mt < 16; ++mt) {
        const int m0 = mt * 64;
        __syncthreads();   // protect ts/Ht from previous chunk's frag reads
        // ---- stage t (16 values per thread: row r, m in [q*16, q*16+16)) ----
#pragma unroll
        for (int g = 0; g < 2; ++g) {
            const int mb = m0 + q * 16 + g * 8;
            float4 a2a = *(const float4*)(A2 + mb);
            float4 a2b = *(const float4*)(A2 + mb + 4);
            const float* mrow = maskg + (size_t)(n0 + r) * N_ + mb;
            float4 mka = *(const float4*)mrow;
            float4 mkb = *(const float4*)(mrow + 4);
            float t0 = __expf(mka.x * lrelu(a1r + a2a.x));
            float t1 = __expf(mka.y * lrelu(a1r + a2a.y));
            float t2 = __expf(mka.z * lrelu(a1r + a2a.z));
            float t3 = __expf(mka.w * lrelu(a1r + a2a.w));
            float t4 = __expf(mkb.x * lrelu(a1r + a2b.x));
            float t5 = __expf(mkb.y * lrelu(a1r + a2b.y));
            float t6 = __expf(mkb.z * lrelu(a1r + a2b.z));
            float t7 = __expf(mkb.w * lrelu(a1r + a2b.w));
            zacc += ((t0 + t1) + (t2 + t3)) + ((t4 + t5) + (t6 + t7));
            bf16x8 pk = {(__bf16)t0, (__bf16)t1, (__bf16)t2, (__bf16)t3,
                         (__bf16)t4, (__bf16)t5, (__bf16)t6, (__bf16)t7};
            *(bf16x8*)&ts[r][q * 16 + g * 8] = pk;
        }
        // ---- stage Ht (row d=r, m in [q*16, q*16+16)) ----
        {
            const bf16x8* src = (const bf16x8*)(Ht_glob + (size_t)r * N_ + m0 + q * 16);
            *(bf16x8*)&Ht[r][q * 16]     = src[0];
            *(bf16x8*)&Ht[r][q * 16 + 8] = src[1];
        }
        __syncthreads();
        // ---- MFMA: wave w owns rows 16w..16w+15, all 4 d-tiles ----
#pragma unroll
        for (int c = 0; c < 2; ++c) {
            bf16x8 af = *(bf16x8*)&ts[16 * w + lo][c * 32 + quad * 8];
#pragma unroll
            for (int t = 0; t < 4; ++t) {
                bf16x8 bfv = *(bf16x8*)&Ht[16 * t + lo][c * 32 + quad * 8];
                acc[t] = mfma_bf16(af, bfv, acc[t]);
            }
        }
    }

    // ---- Z reduce (4 m-quarter threads per row are lanes L^1, L^2) ----
    zacc += __shfl_xor(zacc, 1);
    zacc += __shfl_xor(zacc, 2);
    if (q == 0) invz[r] = 1.f / zacc;
    __syncthreads();

    // ---- epilogue: C/D layout col=lo (d), row=quad*4+i (n) ----
#pragma unroll
    for (int t = 0; t < 4; ++t) {
#pragma unroll
        for (int i = 0; i < 4; ++i) {
            const int n = 16 * w + quad * 4 + i;
            const int d = 16 * t + lo;
            float val = eluf(acc[t][i] * invz[n]);
            if (xc_out)
                xc_out[((size_t)(b * N_ + n0 + n)) * 256 + head * 64 + d] = val;
            else
                out_f[((size_t)(b * N_ + n0 + n)) * 64 + d] = val;
        }
    }

    if (attn_f) {   // layer 2: recompute t rows * invz (fp32, coalesced)
        for (int i = 0; i < 256; ++i) {
            int idx = i * 256 + tid;
            int rr = idx >> 10, m = idx & 1023;
            float s = A1s[rr] + A2[m];
            float mv = maskg[(size_t)(n0 + rr) * N_ + m];
            attn_f[((size_t)(b * N_ + n0 + rr)) * N_ + m] = __expf(mv * lrelu(s)) * invz[rr];
        }
    }
}

// ---------------------------------------------------------------------------
extern "C" void kernel_launch(void* const* d_in, const int* in_sizes, int n_in,
                              void* d_out, int out_size, void* d_ws, size_t ws_size,
                              hipStream_t stream)
{
    const float* x    = (const float*)d_in[0];
    const float* mask = (const float*)d_in[1];
    const float* W1   = (const float*)d_in[2];
    const float* W2   = (const float*)d_in[3];
    const float* a    = (const float*)d_in[4];
    const float* W1o  = (const float*)d_in[5];
    const float* W2o  = (const float*)d_in[6];
    const float* ao   = (const float*)d_in[7];

    float* out      = (float*)d_out;                 // [16,1024,64] fp32
    float* attn_out = out + (size_t)B_ * N_ * 64;    // [16,1024,1024] fp32

    // ws layout: fp32 block then bf16 block (~28 MB total)
    float*  ws  = (float*)d_ws;
    float*  xc  = ws;                   // 16*1024*256      = 4194304 f
    float*  A1  = xc  + 4194304;        // 4*16*1024        = 65536 f
    float*  A2  = A1  + 65536;          // 65536 f
    float*  A1o = A2  + 65536;          // 16384 f
    float*  A2o = A1o + 16384;          // 16384 f
    __bf16* h1t = (__bf16*)(A2o + 16384);   // 4*16*64*1024 = 4194304 bf16
    __bf16* h2t = h1t + 4194304;            // 16*64*1024   = 1048576 bf16

    proj1_kernel    <<<dim3(16, 16, 4), 256, 0, stream>>>(x, W1, W2, a, h1t, A1, A2);
    attn_mfma_kernel<<<dim3(16, 16, 4), 256, 0, stream>>>(A1, A2, h1t, mask, xc, nullptr, nullptr);
    proj2_kernel    <<<dim3(16, 16, 1), 256, 0, stream>>>(xc, W1o, W2o, ao, h2t, A1o, A2o);
    attn_mfma_kernel<<<dim3(16, 16, 1), 256, 0, stream>>>(A1o, A2o, h2t, mask, nullptr, out, attn_out);
}

// Round 5
// 177.359 us; speedup vs baseline: 1.9913x; 1.4245x over previous
//
#include <hip/hip_runtime.h>
#include <hip/hip_bf16.h>

#define B_      16
#define N_      1024
#define ALPHA_  0.2f

typedef __attribute__((ext_vector_type(8))) __bf16 bf16x8;
typedef __attribute__((ext_vector_type(4))) float  floatx4;

__device__ __forceinline__ float eluf(float u) { return u > 0.f ? u : __expf(u) - 1.f; }

__device__ __forceinline__ floatx4 mfma_bf16(bf16x8 a, bf16x8 b, floatx4 c) {
    return __builtin_amdgcn_mfma_f32_16x16x32_bf16(a, b, c, 0, 0, 0);
}

// 4 attention weights t = exp(mask*lrelu(a1+a2)) via separable exp:
// s>0: e^{a1}e^{a2}; s<=0: e^{.2a1}e^{.2a2}; mask==0 -> 1.  (mask is exactly 0/1)
__device__ __forceinline__ void t_quad(const float4 a2v, const float4 ep, const float4 en,
                                       const float4 mv, const float th,
                                       const float e1p, const float e1n,
                                       float& z, float* o)
{
    float t0 = ((a2v.x > th) ? ep.x : en.x) * ((a2v.x > th) ? e1p : e1n);
    float t1 = ((a2v.y > th) ? ep.y : en.y) * ((a2v.y > th) ? e1p : e1n);
    float t2 = ((a2v.z > th) ? ep.z : en.z) * ((a2v.z > th) ? e1p : e1n);
    float t3 = ((a2v.w > th) ? ep.w : en.w) * ((a2v.w > th) ? e1p : e1n);
    t0 = (mv.x != 0.f) ? t0 : 1.f;
    t1 = (mv.y != 0.f) ? t1 : 1.f;
    t2 = (mv.z != 0.f) ? t2 : 1.f;
    t3 = (mv.w != 0.f) ? t3 : 1.f;
    z += ((t0 + t1) + (t2 + t3));
    o[0] = t0; o[1] = t1; o[2] = t2; o[3] = t3;
}

// ---------------------------------------------------------------------------
// proj1: h = x[b,n0:n0+64,:64] @ (n0<512 ? W1[head] : W2[head])   (fp32 math)
// writes h1t[(head*16+b)*64 + d][m] (bf16, transposed) + A1/A2 fp32.
__global__ __launch_bounds__(256) void proj1_kernel(
    const float* __restrict__ x, const float* __restrict__ W1,
    const float* __restrict__ W2, const float* __restrict__ av,
    __bf16* __restrict__ h1t, float* __restrict__ A1, float* __restrict__ A2)
{
    const int tile = blockIdx.x, b = blockIdx.y, head = blockIdx.z;
    const int n0 = tile * 64;
    const float* W  = ((n0 < 512) ? W1 : W2) + head * 64 * 64;
    const float* ah = av + head * 128;

    __shared__ __align__(16) float xs[64][65];
    __shared__ __align__(16) float Wl[64][64];
    __shared__ __align__(16) float as_[128];

    const int tid = threadIdx.x;
    for (int i = 0; i < 16; ++i) {
        int idx = i * 256 + tid;
        int r = idx >> 6, f = idx & 63;
        xs[r][f] = x[(size_t)(b * N_ + n0 + r) * 64 + f];
        Wl[r][f] = W[idx];                       // Wl[f][c]
    }
    if (tid < 128) as_[tid] = ah[tid];
    __syncthreads();

    const int r = tid >> 2, c0 = (tid & 3) * 16;
    float acc[16];
#pragma unroll
    for (int j = 0; j < 16; ++j) acc[j] = 0.f;
#pragma unroll 8
    for (int f = 0; f < 64; ++f) {
        float xv = xs[r][f];
#pragma unroll
        for (int j = 0; j < 16; ++j) acc[j] += xv * Wl[f][c0 + j];
    }

    float p1 = 0.f, p2 = 0.f;
#pragma unroll
    for (int j = 0; j < 16; ++j) {
        p1 += acc[j] * as_[c0 + j];
        p2 += acc[j] * as_[64 + c0 + j];
    }
    p1 += __shfl_xor(p1, 1); p1 += __shfl_xor(p1, 2);
    p2 += __shfl_xor(p2, 1); p2 += __shfl_xor(p2, 2);
    const int bh = head * B_ + b;
    if ((tid & 3) == 0) {
        A1[bh * N_ + n0 + r] = p1;
        A2[bh * N_ + n0 + r] = p2;
    }

    // bounce h through xs (overwrite) -> transposed bf16 global
    __syncthreads();
#pragma unroll
    for (int j = 0; j < 16; ++j) xs[r][c0 + j] = acc[j];
    __syncthreads();
    const int d = tid & 63, ch = tid >> 6;
    bf16x8 q0, q1;
#pragma unroll
    for (int j = 0; j < 8; ++j) q0[j] = (__bf16)xs[ch * 16 + j][d];
#pragma unroll
    for (int j = 0; j < 8; ++j) q1[j] = (__bf16)xs[ch * 16 + 8 + j][d];
    bf16x8* dst = (bf16x8*)(h1t + ((size_t)bh * 64 + d) * N_ + n0 + ch * 16);
    dst[0] = q0; dst[1] = q1;
}

// ---------------------------------------------------------------------------
// attn layer 1: MFMA t.H with separable-exp staging + prefetch; xc out (bf16).
__global__ __launch_bounds__(256, 4) void attn1_kernel(
    const float* __restrict__ A1g, const float* __restrict__ A2g,
    const __bf16* __restrict__ Htg, const float* __restrict__ maskg,
    __bf16* __restrict__ xc_out)
{
    const int tile = blockIdx.x, b = blockIdx.y, head = blockIdx.z;
    const int n0 = tile * 64;
    const int bh = head * B_ + b;
    const float* A1 = A1g + (size_t)bh * N_;
    const float* A2 = A2g + (size_t)bh * N_;
    const __bf16* Hglob = Htg + (size_t)bh * 64 * N_;

    __shared__ __align__(16) __bf16 ts[64][72];
    __shared__ __align__(16) __bf16 Ht[64][72];
    __shared__ __align__(16) float E2p[N_], E2n[N_], A2s[N_];
    __shared__ float invz[64];

    const int tid = threadIdx.x;
#pragma unroll
    for (int i = 0; i < 4; ++i) {
        int m = i * 256 + tid;
        float a2 = A2[m];
        A2s[m] = a2; E2p[m] = __expf(a2); E2n[m] = __expf(ALPHA_ * a2);
    }

    const int r = tid >> 2, q = tid & 3;
    const float a1r = A1[n0 + r];
    const float e1p = __expf(a1r), e1n = __expf(ALPHA_ * a1r), th = -a1r;
    const int w = tid >> 6, L = tid & 63, quad = L >> 4, lo = L & 15;

    floatx4 acc[4] = {{0,0,0,0},{0,0,0,0},{0,0,0,0},{0,0,0,0}};
    float zacc = 0.f;

    const float* mrow = maskg + (size_t)(n0 + r) * N_ + q * 16;
    const __bf16* hrow = Hglob + (size_t)r * N_ + q * 16;
    float4 pm0 = *(const float4*)(mrow);
    float4 pm1 = *(const float4*)(mrow + 4);
    float4 pm2 = *(const float4*)(mrow + 8);
    float4 pm3 = *(const float4*)(mrow + 12);
    bf16x8 ph0 = *(const bf16x8*)(hrow);
    bf16x8 ph1 = *(const bf16x8*)(hrow + 8);

    for (int mt = 0; mt < 16; ++mt) {
        float4 cm0 = pm0, cm1 = pm1, cm2 = pm2, cm3 = pm3;
        bf16x8 ch0 = ph0, ch1 = ph1;
        if (mt < 15) {  // prefetch next chunk; lands during this chunk's MFMA phase
            const float* mnx = mrow + (mt + 1) * 64;
            const __bf16* hnx = hrow + (mt + 1) * 64;
            pm0 = *(const float4*)(mnx);      pm1 = *(const float4*)(mnx + 4);
            pm2 = *(const float4*)(mnx + 8);  pm3 = *(const float4*)(mnx + 12);
            ph0 = *(const bf16x8*)(hnx);      ph1 = *(const bf16x8*)(hnx + 8);
        }
        __syncthreads();   // prev MFMA phase done reading ts/Ht (covers tables on mt=0)
        const int mb = mt * 64 + q * 16;
        float o[16];
        t_quad(*(const float4*)&A2s[mb+0],  *(const float4*)&E2p[mb+0],  *(const float4*)&E2n[mb+0],  cm0, th, e1p, e1n, zacc, o+0);
        t_quad(*(const float4*)&A2s[mb+4],  *(const float4*)&E2p[mb+4],  *(const float4*)&E2n[mb+4],  cm1, th, e1p, e1n, zacc, o+4);
        t_quad(*(const float4*)&A2s[mb+8],  *(const float4*)&E2p[mb+8],  *(const float4*)&E2n[mb+8],  cm2, th, e1p, e1n, zacc, o+8);
        t_quad(*(const float4*)&A2s[mb+12], *(const float4*)&E2p[mb+12], *(const float4*)&E2n[mb+12], cm3, th, e1p, e1n, zacc, o+12);
        bf16x8 pk0 = {(__bf16)o[0], (__bf16)o[1], (__bf16)o[2], (__bf16)o[3],
                      (__bf16)o[4], (__bf16)o[5], (__bf16)o[6], (__bf16)o[7]};
        bf16x8 pk1 = {(__bf16)o[8], (__bf16)o[9], (__bf16)o[10], (__bf16)o[11],
                      (__bf16)o[12], (__bf16)o[13], (__bf16)o[14], (__bf16)o[15]};
        *(bf16x8*)&ts[r][q * 16]     = pk0;
        *(bf16x8*)&ts[r][q * 16 + 8] = pk1;
        *(bf16x8*)&Ht[r][q * 16]     = ch0;
        *(bf16x8*)&Ht[r][q * 16 + 8] = ch1;
        __syncthreads();
#pragma unroll
        for (int c = 0; c < 2; ++c) {
            bf16x8 af = *(bf16x8*)&ts[16 * w + lo][c * 32 + quad * 8];
#pragma unroll
            for (int t = 0; t < 4; ++t) {
                bf16x8 bv = *(bf16x8*)&Ht[16 * t + lo][c * 32 + quad * 8];
                acc[t] = mfma_bf16(af, bv, acc[t]);
            }
        }
    }

    zacc += __shfl_xor(zacc, 1);
    zacc += __shfl_xor(zacc, 2);
    if (q == 0) invz[r] = 1.f / zacc;
    __syncthreads();

    // epilogue: elu(acc*invz) -> bf16, bounce via ts -> coalesced xc stores
#pragma unroll
    for (int t = 0; t < 4; ++t)
#pragma unroll
        for (int i = 0; i < 4; ++i) {
            const int n = 16 * w + quad * 4 + i;
            ts[n][16 * t + lo] = (__bf16)eluf(acc[t][i] * invz[n]);
        }
    __syncthreads();
#pragma unroll
    for (int i = 0; i < 2; ++i) {
        int cid = i * 256 + tid;             // 512 chunks of 8 bf16
        int row = cid >> 3, c8 = (cid & 7) * 8;
        bf16x8 v = *(bf16x8*)&ts[row][c8];
        *(bf16x8*)(xc_out + ((size_t)(b * N_ + n0 + row)) * 256 + head * 64 + c8) = v;
    }
}

// ---------------------------------------------------------------------------
// attn layer 2: same core; outputs fp32 out (elu) + fp32 attn rows (t*invz).
__global__ __launch_bounds__(256) void attn2_kernel(
    const float* __restrict__ A1g, const float* __restrict__ A2g,
    const __bf16* __restrict__ Htg, const float* __restrict__ maskg,
    float* __restrict__ out_f, float* __restrict__ attn_f)
{
    const int tile = blockIdx.x, b = blockIdx.y;
    const int n0 = tile * 64;
    const float* A1 = A1g + (size_t)b * N_;
    const float* A2 = A2g + (size_t)b * N_;
    const __bf16* Hglob = Htg + (size_t)b * 64 * N_;

    __shared__ __align__(16) __bf16 ts[64][72];
    __shared__ __align__(16) __bf16 Ht[64][72];
    __shared__ __align__(16) float E2p[N_], E2n[N_], A2s[N_];
    __shared__ float invz[64], E1pl[64], E1nl[64], A1sl[64];

    const int tid = threadIdx.x;
#pragma unroll
    for (int i = 0; i < 4; ++i) {
        int m = i * 256 + tid;
        float a2 = A2[m];
        A2s[m] = a2; E2p[m] = __expf(a2); E2n[m] = __expf(ALPHA_ * a2);
    }

    const int r = tid >> 2, q = tid & 3;
    const float a1r = A1[n0 + r];
    const float e1p = __expf(a1r), e1n = __expf(ALPHA_ * a1r), th = -a1r;
    if (q == 0) { E1pl[r] = e1p; E1nl[r] = e1n; A1sl[r] = a1r; }
    const int w = tid >> 6, L = tid & 63, quad = L >> 4, lo = L & 15;

    floatx4 acc[4] = {{0,0,0,0},{0,0,0,0},{0,0,0,0},{0,0,0,0}};
    float zacc = 0.f;

    const float* mrow = maskg + (size_t)(n0 + r) * N_ + q * 16;
    const __bf16* hrow = Hglob + (size_t)r * N_ + q * 16;
    float4 pm0 = *(const float4*)(mrow);
    float4 pm1 = *(const float4*)(mrow + 4);
    float4 pm2 = *(const float4*)(mrow + 8);
    float4 pm3 = *(const float4*)(mrow + 12);
    bf16x8 ph0 = *(const bf16x8*)(hrow);
    bf16x8 ph1 = *(const bf16x8*)(hrow + 8);

    for (int mt = 0; mt < 16; ++mt) {
        float4 cm0 = pm0, cm1 = pm1, cm2 = pm2, cm3 = pm3;
        bf16x8 ch0 = ph0, ch1 = ph1;
        if (mt < 15) {
            const float* mnx = mrow + (mt + 1) * 64;
            const __bf16* hnx = hrow + (mt + 1) * 64;
            pm0 = *(const float4*)(mnx);      pm1 = *(const float4*)(mnx + 4);
            pm2 = *(const float4*)(mnx + 8);  pm3 = *(const float4*)(mnx + 12);
            ph0 = *(const bf16x8*)(hnx);      ph1 = *(const bf16x8*)(hnx + 8);
        }
        __syncthreads();
        const int mb = mt * 64 + q * 16;
        float o[16];
        t_quad(*(const float4*)&A2s[mb+0],  *(const float4*)&E2p[mb+0],  *(const float4*)&E2n[mb+0],  cm0, th, e1p, e1n, zacc, o+0);
        t_quad(*(const float4*)&A2s[mb+4],  *(const float4*)&E2p[mb+4],  *(const float4*)&E2n[mb+4],  cm1, th, e1p, e1n, zacc, o+4);
        t_quad(*(const float4*)&A2s[mb+8],  *(const float4*)&E2p[mb+8],  *(const float4*)&E2n[mb+8],  cm2, th, e1p, e1n, zacc, o+8);
        t_quad(*(const float4*)&A2s[mb+12], *(const float4*)&E2p[mb+12], *(const float4*)&E2n[mb+12], cm3, th, e1p, e1n, zacc, o+12);
        bf16x8 pk0 = {(__bf16)o[0], (__bf16)o[1], (__bf16)o[2], (__bf16)o[3],
                      (__bf16)o[4], (__bf16)o[5], (__bf16)o[6], (__bf16)o[7]};
        bf16x8 pk1 = {(__bf16)o[8], (__bf16)o[9], (__bf16)o[10], (__bf16)o[11],
                      (__bf16)o[12], (__bf16)o[13], (__bf16)o[14], (__bf16)o[15]};
        *(bf16x8*)&ts[r][q * 16]     = pk0;
        *(bf16x8*)&ts[r][q * 16 + 8] = pk1;
        *(bf16x8*)&Ht[r][q * 16]     = ch0;
        *(bf16x8*)&Ht[r][q * 16 + 8] = ch1;
        __syncthreads();
#pragma unroll
        for (int c = 0; c < 2; ++c) {
            bf16x8 af = *(bf16x8*)&ts[16 * w + lo][c * 32 + quad * 8];
#pragma unroll
            for (int t = 0; t < 4; ++t) {
                bf16x8 bv = *(bf16x8*)&Ht[16 * t + lo][c * 32 + quad * 8];
                acc[t] = mfma_bf16(af, bv, acc[t]);
            }
        }
    }

    zacc += __shfl_xor(zacc, 1);
    zacc += __shfl_xor(zacc, 2);
    if (q == 0) invz[r] = 1.f / zacc;
    __syncthreads();

    // out = elu(acc*invz)
#pragma unroll
    for (int t = 0; t < 4; ++t)
#pragma unroll
        for (int i = 0; i < 4; ++i) {
            const int n = 16 * w + quad * 4 + i;
            out_f[((size_t)(b * N_ + n0 + n)) * 64 + 16 * t + lo] = eluf(acc[t][i] * invz[n]);
        }

    // attn tail: per row, 1 float4 mask load + select math + 1 float4 store
    const float4 a2v = *(const float4*)&A2s[tid * 4];
    const float4 epv = *(const float4*)&E2p[tid * 4];
    const float4 env = *(const float4*)&E2n[tid * 4];
#pragma unroll 2
    for (int i = 0; i < 64; ++i) {
        const float e1pr = E1pl[i], e1nr = E1nl[i], thr = -A1sl[i], iz = invz[i];
        float4 mv = *(const float4*)(maskg + (size_t)(n0 + i) * N_ + tid * 4);
        float4 res;
        res.x = ((mv.x != 0.f) ? ((a2v.x > thr) ? epv.x * e1pr : env.x * e1nr) : 1.f) * iz;
        res.y = ((mv.y != 0.f) ? ((a2v.y > thr) ? epv.y * e1pr : env.y * e1nr) : 1.f) * iz;
        res.z = ((mv.z != 0.f) ? ((a2v.z > thr) ? epv.z * e1pr : env.z * e1nr) : 1.f) * iz;
        res.w = ((mv.w != 0.f) ? ((a2v.w > thr) ? epv.w * e1pr : env.w * e1nr) : 1.f) * iz;
        *(float4*)(attn_f + ((size_t)(b * N_ + n0 + i)) * N_ + tid * 4) = res;
    }
}

// ---------------------------------------------------------------------------
// proj2: h2 = xc_bf16 @ (n0<512 ? W1o : W2o) via MFMA (K=256); ao-dots + h2t out.
__global__ __launch_bounds__(256) void proj2_kernel(
    const __bf16* __restrict__ xcb, const float* __restrict__ W1o,
    const float* __restrict__ W2o, const float* __restrict__ ao,
    __bf16* __restrict__ h2t, float* __restrict__ A1o, float* __restrict__ A2o)
{
    const int tile = blockIdx.x, b = blockIdx.y;
    const int n0 = tile * 64;
    const float* W = (n0 < 512) ? W1o : W2o;

    __shared__ __align__(16) __bf16 xs[64][264];   // stride 264: 16B-aligned rows, 2-way-free frags
    __shared__ __align__(16) __bf16 Wt[64][264];   // W^T [n][k]
    __shared__ __align__(16) float as_[128];

    const int tid = threadIdx.x;
    if (tid < 128) as_[tid] = ao[tid];

    // stage xc tile (64 x 256 bf16)
#pragma unroll
    for (int i = 0; i < 8; ++i) {
        int idx = i * 256 + tid;
        int row = idx >> 5, c = (idx & 31) * 8;
        *(bf16x8*)&xs[row][c] =
            *(const bf16x8*)(xcb + ((size_t)(b * N_ + n0 + row)) * 256 + c);
    }
    // stage W transposed (256x64 fp32 -> Wt[n][k] bf16)
#pragma unroll
    for (int i = 0; i < 16; ++i) {
        int idx = i * 256 + tid;
        int k = idx >> 4, n4 = (idx & 15) * 4;
        float4 wv = *(const float4*)(W + (size_t)k * 64 + n4);
        Wt[n4 + 0][k] = (__bf16)wv.x;
        Wt[n4 + 1][k] = (__bf16)wv.y;
        Wt[n4 + 2][k] = (__bf16)wv.z;
        Wt[n4 + 3][k] = (__bf16)wv.w;
    }
    __syncthreads();

    const int w = tid >> 6, L = tid & 63, quad = L >> 4, lo = L & 15;
    floatx4 acc[4] = {{0,0,0,0},{0,0,0,0},{0,0,0,0},{0,0,0,0}};
#pragma unroll
    for (int kc = 0; kc < 8; ++kc) {
        bf16x8 af = *(bf16x8*)&xs[16 * w + lo][kc * 32 + quad * 8];
#pragma unroll
        for (int t = 0; t < 4; ++t) {
            bf16x8 bv = *(bf16x8*)&Wt[16 * t + lo][kc * 32 + quad * 8];
            acc[t] = mfma_bf16(af, bv, acc[t]);
        }
    }

    // ao-dots from C-layout: reduce over d = 16t+lo (shfl over lo bits)
    float p1[4] = {0, 0, 0, 0}, p2[4] = {0, 0, 0, 0};
#pragma unroll
    for (int t = 0; t < 4; ++t) {
        float a1w = as_[16 * t + lo], a2w = as_[64 + 16 * t + lo];
#pragma unroll
        for (int i = 0; i < 4; ++i) { p1[i] += acc[t][i] * a1w; p2[i] += acc[t][i] * a2w; }
    }
#pragma unroll
    for (int s = 1; s < 16; s <<= 1)
#pragma unroll
        for (int i = 0; i < 4; ++i) {
            p1[i] += __shfl_xor(p1[i], s);
            p2[i] += __shfl_xor(p2[i], s);
        }
    if (lo == 0) {
#pragma unroll
        for (int i = 0; i < 4; ++i) {
            int n = 16 * w + quad * 4 + i;
            A1o[b * N_ + n0 + n] = p1[i];
            A2o[b * N_ + n0 + n] = p2[i];
        }
    }

    // h2 -> transposed bf16 via xs bounce
    __syncthreads();
#pragma unroll
    for (int t = 0; t < 4; ++t)
#pragma unroll
        for (int i = 0; i < 4; ++i)
            xs[16 * w + quad * 4 + i][16 * t + lo] = (__bf16)acc[t][i];
    __syncthreads();
    const int d = tid & 63, ch = tid >> 6;
    bf16x8 v0, v1;
#pragma unroll
    for (int j = 0; j < 8; ++j) v0[j] = xs[ch * 16 + j][d];
#pragma unroll
    for (int j = 0; j < 8; ++j) v1[j] = xs[ch * 16 + 8 + j][d];
    bf16x8* dst = (bf16x8*)(h2t + ((size_t)b * 64 + d) * N_ + n0 + ch * 16);
    dst[0] = v0; dst[1] = v1;
}

// ---------------------------------------------------------------------------
extern "C" void kernel_launch(void* const* d_in, const int* in_sizes, int n_in,
                              void* d_out, int out_size, void* d_ws, size_t ws_size,
                              hipStream_t stream)
{
    const float* x    = (const float*)d_in[0];
    const float* mask = (const float*)d_in[1];
    const float* W1   = (const float*)d_in[2];
    const float* W2   = (const float*)d_in[3];
    const float* a    = (const float*)d_in[4];
    const float* W1o  = (const float*)d_in[5];
    const float* W2o  = (const float*)d_in[6];
    const float* ao   = (const float*)d_in[7];

    float* out      = (float*)d_out;                 // [16,1024,64] fp32
    float* attn_out = out + (size_t)B_ * N_ * 64;    // [16,1024,1024] fp32

    // ws layout (~19.5 MB)
    float*  ws  = (float*)d_ws;
    float*  A1  = ws;                       // 65536 f
    float*  A2  = A1 + 65536;               // 65536 f
    float*  A1o = A2 + 65536;               // 16384 f
    float*  A2o = A1o + 16384;              // 16384 f
    __bf16* h1t = (__bf16*)(A2o + 16384);   // 4*16*64*1024 = 4194304 bf16
    __bf16* h2t = h1t + 4194304;            // 16*64*1024   = 1048576 bf16
    __bf16* xcb = h2t + 1048576;            // 16*1024*256  = 4194304 bf16

    proj1_kernel<<<dim3(16, 16, 4), 256, 0, stream>>>(x, W1, W2, a, h1t, A1, A2);
    attn1_kernel<<<dim3(16, 16, 4), 256, 0, stream>>>(A1, A2, h1t, mask, xcb);
    proj2_kernel<<<dim3(16, 16, 1), 256, 0, stream>>>(xcb, W1o, W2o, ao, h2t, A1o, A2o);
    attn2_kernel<<<dim3(16, 16, 1), 256, 0, stream>>>(A1o, A2o, h2t, mask, out, attn_out);
}

// Round 6
// 168.545 us; speedup vs baseline: 2.0955x; 1.0523x over previous
//
#include <hip/hip_runtime.h>
#include <hip/hip_bf16.h>

#define B_      16
#define N_      1024
#define ALPHA_  0.2f

typedef __attribute__((ext_vector_type(8))) __bf16 bf16x8;
typedef __attribute__((ext_vector_type(4))) __bf16 bf16x4;
typedef __attribute__((ext_vector_type(4))) float  floatx4;

__device__ __forceinline__ float eluf(float u) { return u > 0.f ? u : __expf(u) - 1.f; }

__device__ __forceinline__ floatx4 mfma_bf16(bf16x8 a, bf16x8 b, floatx4 c) {
    return __builtin_amdgcn_mfma_f32_16x16x32_bf16(a, b, c, 0, 0, 0);
}

// 4 attention weights t = exp(mask*lrelu(a1+a2)) via separable exp:
// s>0: e^{a1}e^{a2}; s<=0: e^{.2a1}e^{.2a2}; mask==0 -> 1.  (mask is exactly 0/1)
__device__ __forceinline__ void t_quad(const float4 a2v, const float4 ep, const float4 en,
                                       const float4 mv, const float th,
                                       const float e1p, const float e1n,
                                       float& z, float* o)
{
    float t0 = ((a2v.x > th) ? ep.x : en.x) * ((a2v.x > th) ? e1p : e1n);
    float t1 = ((a2v.y > th) ? ep.y : en.y) * ((a2v.y > th) ? e1p : e1n);
    float t2 = ((a2v.z > th) ? ep.z : en.z) * ((a2v.z > th) ? e1p : e1n);
    float t3 = ((a2v.w > th) ? ep.w : en.w) * ((a2v.w > th) ? e1p : e1n);
    t0 = (mv.x != 0.f) ? t0 : 1.f;
    t1 = (mv.y != 0.f) ? t1 : 1.f;
    t2 = (mv.z != 0.f) ? t2 : 1.f;
    t3 = (mv.w != 0.f) ? t3 : 1.f;
    z += ((t0 + t1) + (t2 + t3));
    o[0] = t0; o[1] = t1; o[2] = t2; o[3] = t3;
}

// ---------------------------------------------------------------------------
// proj1 (MFMA): h = x[b,n0:n0+64,:64] @ (n0<512 ? W1[head] : W2[head])
// writes h1t[(head*16+b)*64 + d][m] bf16 (transposed) + A1/A2 fp32 dots.
__global__ __launch_bounds__(256) void proj1_kernel(
    const float* __restrict__ x, const float* __restrict__ W1,
    const float* __restrict__ W2, const float* __restrict__ av,
    __bf16* __restrict__ h1t, float* __restrict__ A1, float* __restrict__ A2)
{
    const int tile = blockIdx.x, b = blockIdx.y, head = blockIdx.z;
    const int n0 = tile * 64;
    const float* W  = ((n0 < 512) ? W1 : W2) + head * 64 * 64;
    const float* ah = av + head * 128;

    __shared__ __align__(16) __bf16 xs[64][72];   // x tile [n][k] bf16
    __shared__ __align__(16) __bf16 Wt[64][72];   // W^T [c][k] bf16
    __shared__ __align__(16) float as_[128];

    const int tid = threadIdx.x;
    if (tid < 128) as_[tid] = ah[tid];
#pragma unroll
    for (int i = 0; i < 4; ++i) {
        int idx = i * 256 + tid;                  // 1024 float4s
        int r = idx >> 4, c = (idx & 15) * 4;
        float4 v = *(const float4*)(x + ((size_t)(b * N_ + n0 + r)) * 64 + c);
        xs[r][c+0] = (__bf16)v.x; xs[r][c+1] = (__bf16)v.y;
        xs[r][c+2] = (__bf16)v.z; xs[r][c+3] = (__bf16)v.w;
        float4 wv = *(const float4*)(W + (size_t)r * 64 + c);   // W[k=r][c..]
        Wt[c+0][r] = (__bf16)wv.x; Wt[c+1][r] = (__bf16)wv.y;
        Wt[c+2][r] = (__bf16)wv.z; Wt[c+3][r] = (__bf16)wv.w;
    }
    __syncthreads();

    const int w = tid >> 6, L = tid & 63, quad = L >> 4, lo = L & 15;
    floatx4 acc[4] = {{0,0,0,0},{0,0,0,0},{0,0,0,0},{0,0,0,0}};
#pragma unroll
    for (int kc = 0; kc < 2; ++kc) {
        bf16x8 af = *(bf16x8*)&xs[16 * w + lo][kc * 32 + quad * 8];
#pragma unroll
        for (int t = 0; t < 4; ++t) {
            bf16x8 bv = *(bf16x8*)&Wt[16 * t + lo][kc * 32 + quad * 8];
            acc[t] = mfma_bf16(af, bv, acc[t]);
        }
    }

    // A1/A2 dots from C-layout (row n = 16w+quad*4+i, col c = 16t+lo)
    float p1[4] = {0, 0, 0, 0}, p2[4] = {0, 0, 0, 0};
#pragma unroll
    for (int t = 0; t < 4; ++t) {
        float a1w = as_[16 * t + lo], a2w = as_[64 + 16 * t + lo];
#pragma unroll
        for (int i = 0; i < 4; ++i) { p1[i] += acc[t][i] * a1w; p2[i] += acc[t][i] * a2w; }
    }
#pragma unroll
    for (int s = 1; s < 16; s <<= 1)
#pragma unroll
        for (int i = 0; i < 4; ++i) {
            p1[i] += __shfl_xor(p1[i], s);
            p2[i] += __shfl_xor(p2[i], s);
        }
    const int bh = head * B_ + b;
    if (lo == 0) {
#pragma unroll
        for (int i = 0; i < 4; ++i) {
            int n = 16 * w + quad * 4 + i;
            A1[bh * N_ + n0 + n] = p1[i];
            A2[bh * N_ + n0 + n] = p2[i];
        }
    }

    // h -> transposed bf16 via xs bounce
    __syncthreads();
#pragma unroll
    for (int t = 0; t < 4; ++t)
#pragma unroll
        for (int i = 0; i < 4; ++i)
            xs[16 * w + quad * 4 + i][16 * t + lo] = (__bf16)acc[t][i];
    __syncthreads();
    const int d = tid & 63, ch = tid >> 6;
    bf16x8 v0, v1;
#pragma unroll
    for (int j = 0; j < 8; ++j) v0[j] = xs[ch * 16 + j][d];
#pragma unroll
    for (int j = 0; j < 8; ++j) v1[j] = xs[ch * 16 + 8 + j][d];
    bf16x8* dst = (bf16x8*)(h1t + ((size_t)bh * 64 + d) * N_ + n0 + ch * 16);
    dst[0] = v0; dst[1] = v1;
}

// ---------------------------------------------------------------------------
// attn layer 1: MFMA t.H with separable-exp staging + prefetch; xc out (bf16).
__global__ __launch_bounds__(256, 4) void attn1_kernel(
    const float* __restrict__ A1g, const float* __restrict__ A2g,
    const __bf16* __restrict__ Htg, const float* __restrict__ maskg,
    __bf16* __restrict__ xc_out)
{
    const int tile = blockIdx.x, b = blockIdx.y, head = blockIdx.z;
    const int n0 = tile * 64;
    const int bh = head * B_ + b;
    const float* A1 = A1g + (size_t)bh * N_;
    const float* A2 = A2g + (size_t)bh * N_;
    const __bf16* Hglob = Htg + (size_t)bh * 64 * N_;

    __shared__ __align__(16) __bf16 ts[64][72];
    __shared__ __align__(16) __bf16 Ht[64][72];
    __shared__ __align__(16) float E2p[N_], E2n[N_], A2s[N_];
    __shared__ float invz[64];

    const int tid = threadIdx.x;
#pragma unroll
    for (int i = 0; i < 4; ++i) {
        int m = i * 256 + tid;
        float a2 = A2[m];
        A2s[m] = a2; E2p[m] = __expf(a2); E2n[m] = __expf(ALPHA_ * a2);
    }

    const int r = tid >> 2, q = tid & 3;
    const float a1r = A1[n0 + r];
    const float e1p = __expf(a1r), e1n = __expf(ALPHA_ * a1r), th = -a1r;
    const int w = tid >> 6, L = tid & 63, quad = L >> 4, lo = L & 15;

    floatx4 acc[4] = {{0,0,0,0},{0,0,0,0},{0,0,0,0},{0,0,0,0}};
    float zacc = 0.f;

    const float* mrow = maskg + (size_t)(n0 + r) * N_ + q * 16;
    const __bf16* hrow = Hglob + (size_t)r * N_ + q * 16;
    float4 pm0 = *(const float4*)(mrow);
    float4 pm1 = *(const float4*)(mrow + 4);
    float4 pm2 = *(const float4*)(mrow + 8);
    float4 pm3 = *(const float4*)(mrow + 12);
    bf16x8 ph0 = *(const bf16x8*)(hrow);
    bf16x8 ph1 = *(const bf16x8*)(hrow + 8);

    for (int mt = 0; mt < 16; ++mt) {
        float4 cm0 = pm0, cm1 = pm1, cm2 = pm2, cm3 = pm3;
        bf16x8 ch0 = ph0, ch1 = ph1;
        if (mt < 15) {
            const float* mnx = mrow + (mt + 1) * 64;
            const __bf16* hnx = hrow + (mt + 1) * 64;
            pm0 = *(const float4*)(mnx);      pm1 = *(const float4*)(mnx + 4);
            pm2 = *(const float4*)(mnx + 8);  pm3 = *(const float4*)(mnx + 12);
            ph0 = *(const bf16x8*)(hnx);      ph1 = *(const bf16x8*)(hnx + 8);
        }
        __syncthreads();
        const int mb = mt * 64 + q * 16;
        float o[16];
        t_quad(*(const float4*)&A2s[mb+0],  *(const float4*)&E2p[mb+0],  *(const float4*)&E2n[mb+0],  cm0, th, e1p, e1n, zacc, o+0);
        t_quad(*(const float4*)&A2s[mb+4],  *(const float4*)&E2p[mb+4],  *(const float4*)&E2n[mb+4],  cm1, th, e1p, e1n, zacc, o+4);
        t_quad(*(const float4*)&A2s[mb+8],  *(const float4*)&E2p[mb+8],  *(const float4*)&E2n[mb+8],  cm2, th, e1p, e1n, zacc, o+8);
        t_quad(*(const float4*)&A2s[mb+12], *(const float4*)&E2p[mb+12], *(const float4*)&E2n[mb+12], cm3, th, e1p, e1n, zacc, o+12);
        bf16x8 pk0 = {(__bf16)o[0], (__bf16)o[1], (__bf16)o[2], (__bf16)o[3],
                      (__bf16)o[4], (__bf16)o[5], (__bf16)o[6], (__bf16)o[7]};
        bf16x8 pk1 = {(__bf16)o[8], (__bf16)o[9], (__bf16)o[10], (__bf16)o[11],
                      (__bf16)o[12], (__bf16)o[13], (__bf16)o[14], (__bf16)o[15]};
        *(bf16x8*)&ts[r][q * 16]     = pk0;
        *(bf16x8*)&ts[r][q * 16 + 8] = pk1;
        *(bf16x8*)&Ht[r][q * 16]     = ch0;
        *(bf16x8*)&Ht[r][q * 16 + 8] = ch1;
        __syncthreads();
#pragma unroll
        for (int c = 0; c < 2; ++c) {
            bf16x8 af = *(bf16x8*)&ts[16 * w + lo][c * 32 + quad * 8];
#pragma unroll
            for (int t = 0; t < 4; ++t) {
                bf16x8 bv = *(bf16x8*)&Ht[16 * t + lo][c * 32 + quad * 8];
                acc[t] = mfma_bf16(af, bv, acc[t]);
            }
        }
    }

    zacc += __shfl_xor(zacc, 1);
    zacc += __shfl_xor(zacc, 2);
    if (q == 0) invz[r] = 1.f / zacc;
    __syncthreads();

#pragma unroll
    for (int t = 0; t < 4; ++t)
#pragma unroll
        for (int i = 0; i < 4; ++i) {
            const int n = 16 * w + quad * 4 + i;
            ts[n][16 * t + lo] = (__bf16)eluf(acc[t][i] * invz[n]);
        }
    __syncthreads();
#pragma unroll
    for (int i = 0; i < 2; ++i) {
        int cid = i * 256 + tid;
        int row = cid >> 3, c8 = (cid & 7) * 8;
        bf16x8 v = *(bf16x8*)&ts[row][c8];
        *(bf16x8*)(xc_out + ((size_t)(b * N_ + n0 + row)) * 256 + head * 64 + c8) = v;
    }
}

// ---------------------------------------------------------------------------
// attn layer 2: 16-row tiles (grid 64,16 -> 1024 blocks, 4 blocks/CU).
// Wave w owns d-tile w (16 cols) for all 16 rows. fp32 out + fp32 attn rows.
__global__ __launch_bounds__(256) void attn2_kernel(
    const float* __restrict__ A1g, const float* __restrict__ A2g,
    const __bf16* __restrict__ Htg, const float* __restrict__ maskg,
    float* __restrict__ out_f, float* __restrict__ attn_f)
{
    const int tile = blockIdx.x, b = blockIdx.y;
    const int n0 = tile * 16;
    const float* A1 = A1g + (size_t)b * N_;
    const float* A2 = A2g + (size_t)b * N_;
    const __bf16* Hglob = Htg + (size_t)b * 64 * N_;

    __shared__ __align__(16) __bf16 ts[16][72];
    __shared__ __align__(16) __bf16 Ht[64][72];
    __shared__ __align__(16) float E2p[N_], E2n[N_], A2s[N_];
    __shared__ float invz[16], E1pl[16], E1nl[16], A1sl[16];

    const int tid = threadIdx.x;
#pragma unroll
    for (int i = 0; i < 4; ++i) {
        int m = i * 256 + tid;
        float a2 = A2[m];
        A2s[m] = a2; E2p[m] = __expf(a2); E2n[m] = __expf(ALPHA_ * a2);
    }

    const int r = tid >> 4, q = tid & 15;          // t-staging: row r, 4 m's at q*4
    const float a1r = A1[n0 + r];
    const float e1p = __expf(a1r), e1n = __expf(ALPHA_ * a1r), th = -a1r;
    if (q == 0) { E1pl[r] = e1p; E1nl[r] = e1n; A1sl[r] = a1r; }
    const int dr = tid >> 2, dq = tid & 3;         // Ht staging: row dr, 16 m's at dq*16
    const int w = tid >> 6, L = tid & 63, quad = L >> 4, lo = L & 15;

    floatx4 acc = {0, 0, 0, 0};
    float zacc = 0.f;

    const float* mrow = maskg + (size_t)(n0 + r) * N_ + q * 4;
    const __bf16* hrow = Hglob + (size_t)dr * N_ + dq * 16;
    float4 pm = *(const float4*)(mrow);
    bf16x8 ph0 = *(const bf16x8*)(hrow);
    bf16x8 ph1 = *(const bf16x8*)(hrow + 8);

    for (int mt = 0; mt < 16; ++mt) {
        float4 cm = pm;
        bf16x8 ch0 = ph0, ch1 = ph1;
        if (mt < 15) {
            pm  = *(const float4*)(mrow + (mt + 1) * 64);
            ph0 = *(const bf16x8*)(hrow + (mt + 1) * 64);
            ph1 = *(const bf16x8*)(hrow + (mt + 1) * 64 + 8);
        }
        __syncthreads();
        const int mb = mt * 64 + q * 4;
        float o[4];
        t_quad(*(const float4*)&A2s[mb], *(const float4*)&E2p[mb],
               *(const float4*)&E2n[mb], cm, th, e1p, e1n, zacc, o);
        bf16x4 pk = {(__bf16)o[0], (__bf16)o[1], (__bf16)o[2], (__bf16)o[3]};
        *(bf16x4*)&ts[r][q * 4] = pk;
        *(bf16x8*)&Ht[dr][dq * 16]     = ch0;
        *(bf16x8*)&Ht[dr][dq * 16 + 8] = ch1;
        __syncthreads();
#pragma unroll
        for (int c = 0; c < 2; ++c) {
            bf16x8 af = *(bf16x8*)&ts[lo][c * 32 + quad * 8];
            bf16x8 bv = *(bf16x8*)&Ht[16 * w + lo][c * 32 + quad * 8];
            acc = mfma_bf16(af, bv, acc);
        }
    }

    zacc += __shfl_xor(zacc, 1);
    zacc += __shfl_xor(zacc, 2);
    zacc += __shfl_xor(zacc, 4);
    zacc += __shfl_xor(zacc, 8);
    if (q == 0) invz[r] = 1.f / zacc;
    __syncthreads();

    // out = elu(acc*invz): C-layout col=lo (n-row? no: col=lo is B's n = row index here)
    // A was t[16 rows n][K], B was Ht[d][K] -> D[col=lo -> n? ] careful:
    // mfma D[r_,c_]: A rows = M (our n, 16), B rows = N (our d, 16 per wave).
    // C/D: col(lane&15) indexes N (d), row(quad*4+i) indexes M (n).
#pragma unroll
    for (int i = 0; i < 4; ++i) {
        const int n = quad * 4 + i;
        out_f[((size_t)(b * N_ + n0 + n)) * 64 + 16 * w + lo] = eluf(acc[i] * invz[n]);
    }

    // attn tail: 16 rows x 1024 m fp32
    const float4 a2v = *(const float4*)&A2s[tid * 4];
    const float4 epv = *(const float4*)&E2p[tid * 4];
    const float4 env = *(const float4*)&E2n[tid * 4];
#pragma unroll 4
    for (int i = 0; i < 16; ++i) {
        const float e1pr = E1pl[i], e1nr = E1nl[i], thr = -A1sl[i], iz = invz[i];
        float4 mv = *(const float4*)(maskg + (size_t)(n0 + i) * N_ + tid * 4);
        float4 res;
        res.x = ((mv.x != 0.f) ? ((a2v.x > thr) ? epv.x * e1pr : env.x * e1nr) : 1.f) * iz;
        res.y = ((mv.y != 0.f) ? ((a2v.y > thr) ? epv.y * e1pr : env.y * e1nr) : 1.f) * iz;
        res.z = ((mv.z != 0.f) ? ((a2v.z > thr) ? epv.z * e1pr : env.z * e1nr) : 1.f) * iz;
        res.w = ((mv.w != 0.f) ? ((a2v.w > thr) ? epv.w * e1pr : env.w * e1nr) : 1.f) * iz;
        *(float4*)(attn_f + ((size_t)(b * N_ + n0 + i)) * N_ + tid * 4) = res;
    }
}

// ---------------------------------------------------------------------------
// proj2: h2 = xc_bf16 @ (n0<512 ? W1o : W2o) via MFMA (K=256); ao-dots + h2t out.
__global__ __launch_bounds__(256) void proj2_kernel(
    const __bf16* __restrict__ xcb, const float* __restrict__ W1o,
    const float* __restrict__ W2o, const float* __restrict__ ao,
    __bf16* __restrict__ h2t, float* __restrict__ A1o, float* __restrict__ A2o)
{
    const int tile = blockIdx.x, b = blockIdx.y;
    const int n0 = tile * 64;
    const float* W = (n0 < 512) ? W1o : W2o;

    __shared__ __align__(16) __bf16 xs[64][264];
    __shared__ __align__(16) __bf16 Wt[64][264];
    __shared__ __align__(16) float as_[128];

    const int tid = threadIdx.x;
    if (tid < 128) as_[tid] = ao[tid];

#pragma unroll
    for (int i = 0; i < 8; ++i) {
        int idx = i * 256 + tid;
        int row = idx >> 5, c = (idx & 31) * 8;
        *(bf16x8*)&xs[row][c] =
            *(const bf16x8*)(xcb + ((size_t)(b * N_ + n0 + row)) * 256 + c);
    }
#pragma unroll
    for (int i = 0; i < 16; ++i) {
        int idx = i * 256 + tid;
        int k = idx >> 4, n4 = (idx & 15) * 4;
        float4 wv = *(const float4*)(W + (size_t)k * 64 + n4);
        Wt[n4 + 0][k] = (__bf16)wv.x;
        Wt[n4 + 1][k] = (__bf16)wv.y;
        Wt[n4 + 2][k] = (__bf16)wv.z;
        Wt[n4 + 3][k] = (__bf16)wv.w;
    }
    __syncthreads();

    const int w = tid >> 6, L = tid & 63, quad = L >> 4, lo = L & 15;
    floatx4 acc[4] = {{0,0,0,0},{0,0,0,0},{0,0,0,0},{0,0,0,0}};
#pragma unroll
    for (int kc = 0; kc < 8; ++kc) {
        bf16x8 af = *(bf16x8*)&xs[16 * w + lo][kc * 32 + quad * 8];
#pragma unroll
        for (int t = 0; t < 4; ++t) {
            bf16x8 bv = *(bf16x8*)&Wt[16 * t + lo][kc * 32 + quad * 8];
            acc[t] = mfma_bf16(af, bv, acc[t]);
        }
    }

    float p1[4] = {0, 0, 0, 0}, p2[4] = {0, 0, 0, 0};
#pragma unroll
    for (int t = 0; t < 4; ++t) {
        float a1w = as_[16 * t + lo], a2w = as_[64 + 16 * t + lo];
#pragma unroll
        for (int i = 0; i < 4; ++i) { p1[i] += acc[t][i] * a1w; p2[i] += acc[t][i] * a2w; }
    }
#pragma unroll
    for (int s = 1; s < 16; s <<= 1)
#pragma unroll
        for (int i = 0; i < 4; ++i) {
            p1[i] += __shfl_xor(p1[i], s);
            p2[i] += __shfl_xor(p2[i], s);
        }
    if (lo == 0) {
#pragma unroll
        for (int i = 0; i < 4; ++i) {
            int n = 16 * w + quad * 4 + i;
            A1o[b * N_ + n0 + n] = p1[i];
            A2o[b * N_ + n0 + n] = p2[i];
        }
    }

    __syncthreads();
#pragma unroll
    for (int t = 0; t < 4; ++t)
#pragma unroll
        for (int i = 0; i < 4; ++i)
            xs[16 * w + quad * 4 + i][16 * t + lo] = (__bf16)acc[t][i];
    __syncthreads();
    const int d = tid & 63, ch = tid >> 6;
    bf16x8 v0, v1;
#pragma unroll
    for (int j = 0; j < 8; ++j) v0[j] = xs[ch * 16 + j][d];
#pragma unroll
    for (int j = 0; j < 8; ++j) v1[j] = xs[ch * 16 + 8 + j][d];
    bf16x8* dst = (bf16x8*)(h2t + ((size_t)b * 64 + d) * N_ + n0 + ch * 16);
    dst[0] = v0; dst[1] = v1;
}

// ---------------------------------------------------------------------------
extern "C" void kernel_launch(void* const* d_in, const int* in_sizes, int n_in,
                              void* d_out, int out_size, void* d_ws, size_t ws_size,
                              hipStream_t stream)
{
    const float* x    = (const float*)d_in[0];
    const float* mask = (const float*)d_in[1];
    const float* W1   = (const float*)d_in[2];
    const float* W2   = (const float*)d_in[3];
    const float* a    = (const float*)d_in[4];
    const float* W1o  = (const float*)d_in[5];
    const float* W2o  = (const float*)d_in[6];
    const float* ao   = (const float*)d_in[7];

    float* out      = (float*)d_out;                 // [16,1024,64] fp32
    float* attn_out = out + (size_t)B_ * N_ * 64;    // [16,1024,1024] fp32

    float*  ws  = (float*)d_ws;
    float*  A1  = ws;                       // 65536 f
    float*  A2  = A1 + 65536;               // 65536 f
    float*  A1o = A2 + 65536;               // 16384 f
    float*  A2o = A1o + 16384;              // 16384 f
    __bf16* h1t = (__bf16*)(A2o + 16384);   // 4*16*64*1024 = 4194304 bf16
    __bf16* h2t = h1t + 4194304;            // 16*64*1024   = 1048576 bf16
    __bf16* xcb = h2t + 1048576;            // 16*1024*256  = 4194304 bf16

    proj1_kernel<<<dim3(16, 16, 4), 256, 0, stream>>>(x, W1, W2, a, h1t, A1, A2);
    attn1_kernel<<<dim3(16, 16, 4), 256, 0, stream>>>(A1, A2, h1t, mask, xcb);
    proj2_kernel<<<dim3(16, 16, 1), 256, 0, stream>>>(xcb, W1o, W2o, ao, h2t, A1o, A2o);
    attn2_kernel<<<dim3(64, 16, 1), 256, 0, stream>>>(A1o, A2o, h2t, mask, out, attn_out);
}

// Round 7
// 155.729 us; speedup vs baseline: 2.2679x; 1.0823x over previous
//
#include <hip/hip_runtime.h>
#include <hip/hip_bf16.h>

#define B_      16
#define N_      1024
#define ALPHA_  0.2f

typedef __attribute__((ext_vector_type(8))) __bf16 bf16x8;
typedef __attribute__((ext_vector_type(4))) float  floatx4;

__device__ __forceinline__ float eluf(float u) { return u > 0.f ? u : __expf(u) - 1.f; }

__device__ __forceinline__ floatx4 mfma_bf16(bf16x8 a, bf16x8 b, floatx4 c) {
    return __builtin_amdgcn_mfma_f32_16x16x32_bf16(a, b, c, 0, 0, 0);
}

// ---------------------------------------------------------------------------
// mask (fp32 0/1, [1024][1024]) -> bit array (32 words per row)
__global__ __launch_bounds__(256) void maskbits_kernel(
    const float* __restrict__ mask, unsigned* __restrict__ bits)
{
    const int idx = blockIdx.x * 256 + threadIdx.x;      // 32768 words
    const float* src = mask + (size_t)idx * 32;
    unsigned v = 0;
#pragma unroll
    for (int j = 0; j < 8; ++j) {
        float4 f = *(const float4*)(src + j * 4);
        v |= ((unsigned)(f.x != 0.f)) << (j * 4 + 0);
        v |= ((unsigned)(f.y != 0.f)) << (j * 4 + 1);
        v |= ((unsigned)(f.z != 0.f)) << (j * 4 + 2);
        v |= ((unsigned)(f.w != 0.f)) << (j * 4 + 3);
    }
    bits[idx] = v;
}

// ---------------------------------------------------------------------------
// proj1 (MFMA): h = x[b,n0:n0+64,:64] @ (n0<512 ? W1[head] : W2[head])
// writes h1t[(head*16+b)*64 + d][m] bf16 (transposed) + A1/A2 fp32 dots.
__global__ __launch_bounds__(256) void proj1_kernel(
    const float* __restrict__ x, const float* __restrict__ W1,
    const float* __restrict__ W2, const float* __restrict__ av,
    __bf16* __restrict__ h1t, float* __restrict__ A1, float* __restrict__ A2)
{
    const int tile = blockIdx.x, b = blockIdx.y, head = blockIdx.z;
    const int n0 = tile * 64;
    const float* W  = ((n0 < 512) ? W1 : W2) + head * 64 * 64;
    const float* ah = av + head * 128;

    __shared__ __align__(16) __bf16 xs[64][72];
    __shared__ __align__(16) __bf16 Wt[64][72];
    __shared__ __align__(16) float as_[128];

    const int tid = threadIdx.x;
    if (tid < 128) as_[tid] = ah[tid];
#pragma unroll
    for (int i = 0; i < 4; ++i) {
        int idx = i * 256 + tid;
        int r = idx >> 4, c = (idx & 15) * 4;
        float4 v = *(const float4*)(x + ((size_t)(b * N_ + n0 + r)) * 64 + c);
        xs[r][c+0] = (__bf16)v.x; xs[r][c+1] = (__bf16)v.y;
        xs[r][c+2] = (__bf16)v.z; xs[r][c+3] = (__bf16)v.w;
        float4 wv = *(const float4*)(W + (size_t)r * 64 + c);
        Wt[c+0][r] = (__bf16)wv.x; Wt[c+1][r] = (__bf16)wv.y;
        Wt[c+2][r] = (__bf16)wv.z; Wt[c+3][r] = (__bf16)wv.w;
    }
    __syncthreads();

    const int w = tid >> 6, L = tid & 63, quad = L >> 4, lo = L & 15;
    floatx4 acc[4] = {{0,0,0,0},{0,0,0,0},{0,0,0,0},{0,0,0,0}};
#pragma unroll
    for (int kc = 0; kc < 2; ++kc) {
        bf16x8 af = *(bf16x8*)&xs[16 * w + lo][kc * 32 + quad * 8];
#pragma unroll
        for (int t = 0; t < 4; ++t) {
            bf16x8 bv = *(bf16x8*)&Wt[16 * t + lo][kc * 32 + quad * 8];
            acc[t] = mfma_bf16(af, bv, acc[t]);
        }
    }

    float p1[4] = {0, 0, 0, 0}, p2[4] = {0, 0, 0, 0};
#pragma unroll
    for (int t = 0; t < 4; ++t) {
        float a1w = as_[16 * t + lo], a2w = as_[64 + 16 * t + lo];
#pragma unroll
        for (int i = 0; i < 4; ++i) { p1[i] += acc[t][i] * a1w; p2[i] += acc[t][i] * a2w; }
    }
#pragma unroll
    for (int s = 1; s < 16; s <<= 1)
#pragma unroll
        for (int i = 0; i < 4; ++i) {
            p1[i] += __shfl_xor(p1[i], s);
            p2[i] += __shfl_xor(p2[i], s);
        }
    const int bh = head * B_ + b;
    if (lo == 0) {
#pragma unroll
        for (int i = 0; i < 4; ++i) {
            int n = 16 * w + quad * 4 + i;
            A1[bh * N_ + n0 + n] = p1[i];
            A2[bh * N_ + n0 + n] = p2[i];
        }
    }

    __syncthreads();
#pragma unroll
    for (int t = 0; t < 4; ++t)
#pragma unroll
        for (int i = 0; i < 4; ++i)
            xs[16 * w + quad * 4 + i][16 * t + lo] = (__bf16)acc[t][i];
    __syncthreads();
    const int d = tid & 63, ch = tid >> 6;
    bf16x8 v0, v1;
#pragma unroll
    for (int j = 0; j < 8; ++j) v0[j] = xs[ch * 16 + j][d];
#pragma unroll
    for (int j = 0; j < 8; ++j) v1[j] = xs[ch * 16 + 8 + j][d];
    bf16x8* dst = (bf16x8*)(h1t + ((size_t)bh * 64 + d) * N_ + n0 + ch * 16);
    dst[0] = v0; dst[1] = v1;
}

// ---------------------------------------------------------------------------
// attn layer 1: grid (b, head, tile) = (16,4,16) so all 16 tiles of one
// (b,head) share an XCD (linear%8 = b%8) -> Ht re-reads hit XCD-local L2.
// Bitmask scores: t = bit ? exp(max(s,.2s)) : 1. xc out bf16.
__global__ __launch_bounds__(256, 4) void attn1_kernel(
    const float* __restrict__ A1g, const float* __restrict__ A2g,
    const __bf16* __restrict__ Htg, const unsigned* __restrict__ bitsG,
    __bf16* __restrict__ xc_out)
{
    const int b = blockIdx.x, head = blockIdx.y, tile = blockIdx.z;
    const int n0 = tile * 64;
    const int bh = head * B_ + b;
    const float* A2 = A2g + (size_t)bh * N_;
    const __bf16* Hglob = Htg + (size_t)bh * 64 * N_;

    __shared__ __align__(16) __bf16 ts[64][72];
    __shared__ __align__(16) __bf16 Ht[64][72];
    __shared__ __align__(16) float A2s[N_];
    __shared__ __align__(16) unsigned bitsS[2048];   // transposed [w32][row64]
    __shared__ float invz[64];

    const int tid = threadIdx.x;
    *(float4*)&A2s[tid * 4] = *(const float4*)(A2 + tid * 4);
    {   // stage bits transposed: src word s=tid*8+k -> row=s>>5 (=tid>>2), w=s&31
        uint4 u0 = *(const uint4*)(bitsG + n0 * 32 + tid * 8);
        uint4 u1 = *(const uint4*)(bitsG + n0 * 32 + tid * 8 + 4);
        const int row = tid >> 2, wb0 = (tid & 3) * 8;
        bitsS[(wb0+0)*64+row] = u0.x; bitsS[(wb0+1)*64+row] = u0.y;
        bitsS[(wb0+2)*64+row] = u0.z; bitsS[(wb0+3)*64+row] = u0.w;
        bitsS[(wb0+4)*64+row] = u1.x; bitsS[(wb0+5)*64+row] = u1.y;
        bitsS[(wb0+6)*64+row] = u1.z; bitsS[(wb0+7)*64+row] = u1.w;
    }

    const int r = tid >> 2, q = tid & 3;
    const float a1r = A1g[(size_t)bh * N_ + n0 + r];
    const int w = tid >> 6, L = tid & 63, quad = L >> 4, lo = L & 15;
    const __bf16* hrow = Hglob + (size_t)r * N_ + q * 16;

    floatx4 acc[4] = {{0,0,0,0},{0,0,0,0},{0,0,0,0},{0,0,0,0}};
    float zacc = 0.f;

    for (int mt = 0; mt < 16; ++mt) {
        __syncthreads();   // prev MFMA done with ts/Ht (mt=0: covers A2s/bits)
        bf16x8 h0 = *(const bf16x8*)(hrow + mt * 64);       // issue early
        bf16x8 h1 = *(const bf16x8*)(hrow + mt * 64 + 8);
        const int mb = mt * 64 + q * 16;
        const unsigned wb = bitsS[(mt * 2 + (q >> 1)) * 64 + r] >> ((q & 1) * 16);
        float o[16];
#pragma unroll
        for (int j = 0; j < 16; ++j) {
            float s = a1r + A2s[mb + j];
            float lr = fmaxf(s, ALPHA_ * s);
            float t = ((wb >> j) & 1u) ? __expf(lr) : 1.f;
            zacc += t; o[j] = t;
        }
        bf16x8 pk0 = {(__bf16)o[0], (__bf16)o[1], (__bf16)o[2], (__bf16)o[3],
                      (__bf16)o[4], (__bf16)o[5], (__bf16)o[6], (__bf16)o[7]};
        bf16x8 pk1 = {(__bf16)o[8], (__bf16)o[9], (__bf16)o[10], (__bf16)o[11],
                      (__bf16)o[12], (__bf16)o[13], (__bf16)o[14], (__bf16)o[15]};
        *(bf16x8*)&ts[r][q * 16]     = pk0;
        *(bf16x8*)&ts[r][q * 16 + 8] = pk1;
        *(bf16x8*)&Ht[r][q * 16]     = h0;
        *(bf16x8*)&Ht[r][q * 16 + 8] = h1;
        __syncthreads();
#pragma unroll
        for (int c = 0; c < 2; ++c) {
            bf16x8 af = *(bf16x8*)&ts[16 * w + lo][c * 32 + quad * 8];
#pragma unroll
            for (int t = 0; t < 4; ++t) {
                bf16x8 bv = *(bf16x8*)&Ht[16 * t + lo][c * 32 + quad * 8];
                acc[t] = mfma_bf16(af, bv, acc[t]);
            }
        }
    }

    zacc += __shfl_xor(zacc, 1);
    zacc += __shfl_xor(zacc, 2);
    if (q == 0) invz[r] = 1.f / zacc;
    __syncthreads();

#pragma unroll
    for (int t = 0; t < 4; ++t)
#pragma unroll
        for (int i = 0; i < 4; ++i) {
            const int n = 16 * w + quad * 4 + i;
            ts[n][16 * t + lo] = (__bf16)eluf(acc[t][i] * invz[n]);
        }
    __syncthreads();
#pragma unroll
    for (int i = 0; i < 2; ++i) {
        int cid = i * 256 + tid;
        int row = cid >> 3, c8 = (cid & 7) * 8;
        bf16x8 v = *(bf16x8*)&ts[row][c8];
        *(bf16x8*)(xc_out + ((size_t)(b * N_ + n0 + row)) * 256 + head * 64 + c8) = v;
    }
}

// ---------------------------------------------------------------------------
// attn layer 2: 32-row tiles, grid (b,1,tile)=(16,1,32) (XCD = b%8).
// t kept in regs (bf16) across the K-loop -> attn tail is pure t*invz stores.
__global__ __launch_bounds__(256) void attn2_kernel(
    const float* __restrict__ A1g, const float* __restrict__ A2g,
    const __bf16* __restrict__ Htg, const unsigned* __restrict__ bitsG,
    float* __restrict__ out_f, float* __restrict__ attn_f)
{
    const int b = blockIdx.x, tile = blockIdx.z;
    const int n0 = tile * 32;
    const float* A2 = A2g + (size_t)b * N_;
    const __bf16* Hglob = Htg + (size_t)b * 64 * N_;

    __shared__ __align__(16) __bf16 ts[32][72];
    __shared__ __align__(16) __bf16 Ht[64][72];
    __shared__ __align__(16) float A2s[N_];
    __shared__ __align__(16) unsigned bitsS[1024];   // transposed [w32][row32]
    __shared__ float invz[32];

    const int tid = threadIdx.x;
    *(float4*)&A2s[tid * 4] = *(const float4*)(A2 + tid * 4);
    {   // src word s=tid*4+k -> row=s>>5 (=tid>>3), w=s&31
        uint4 u = *(const uint4*)(bitsG + n0 * 32 + tid * 4);
        const int row = tid >> 3, wb0 = (tid & 7) * 4;
        bitsS[(wb0+0)*32+row] = u.x; bitsS[(wb0+1)*32+row] = u.y;
        bitsS[(wb0+2)*32+row] = u.z; bitsS[(wb0+3)*32+row] = u.w;
    }

    const int r2 = tid >> 3, q2 = tid & 7;          // t-staging: row r2, 8 m's
    const float a1r = A1g[(size_t)b * N_ + n0 + r2];
    const int dr = tid >> 2, dq = tid & 3;          // Ht staging
    const int w = tid >> 6, L = tid & 63, quad = L >> 4, lo = L & 15;
    const __bf16* hrow = Hglob + (size_t)dr * N_ + dq * 16;

    floatx4 acc2[2] = {{0,0,0,0},{0,0,0,0}};
    float zacc = 0.f;
    bf16x8 tr[16];

    for (int mt = 0; mt < 16; ++mt) {
        __syncthreads();
        bf16x8 h0 = *(const bf16x8*)(hrow + mt * 64);
        bf16x8 h1 = *(const bf16x8*)(hrow + mt * 64 + 8);
        const int mb = mt * 64 + q2 * 8;
        const unsigned wb = bitsS[(mt * 2 + (q2 >> 2)) * 32 + r2] >> ((q2 & 3) * 8);
        float o[8];
#pragma unroll
        for (int j = 0; j < 8; ++j) {
            float s = a1r + A2s[mb + j];
            float lr = fmaxf(s, ALPHA_ * s);
            float t = ((wb >> j) & 1u) ? __expf(lr) : 1.f;
            zacc += t; o[j] = t;
        }
        bf16x8 pk = {(__bf16)o[0], (__bf16)o[1], (__bf16)o[2], (__bf16)o[3],
                     (__bf16)o[4], (__bf16)o[5], (__bf16)o[6], (__bf16)o[7]};
        tr[mt] = pk;
        *(bf16x8*)&ts[r2][q2 * 8] = pk;
        *(bf16x8*)&Ht[dr][dq * 16]     = h0;
        *(bf16x8*)&Ht[dr][dq * 16 + 8] = h1;
        __syncthreads();
#pragma unroll
        for (int c = 0; c < 2; ++c) {
#pragma unroll
            for (int rt = 0; rt < 2; ++rt) {
                bf16x8 af = *(bf16x8*)&ts[16 * rt + lo][c * 32 + quad * 8];
                bf16x8 bv = *(bf16x8*)&Ht[16 * w + lo][c * 32 + quad * 8];
                acc2[rt] = mfma_bf16(af, bv, acc2[rt]);
            }
        }
    }

    zacc += __shfl_xor(zacc, 1);
    zacc += __shfl_xor(zacc, 2);
    zacc += __shfl_xor(zacc, 4);
    if (q2 == 0) invz[r2] = 1.f / zacc;
    __syncthreads();

    // out = elu(acc*invz): wave w owns d cols 16w+lo; rows rt*16+quad*4+i
#pragma unroll
    for (int rt = 0; rt < 2; ++rt)
#pragma unroll
        for (int i = 0; i < 4; ++i) {
            const int n = 16 * rt + quad * 4 + i;
            out_f[((size_t)(b * N_ + n0 + n)) * 64 + 16 * w + lo] =
                eluf(acc2[rt][i] * invz[n]);
        }

    // attn tail from saved t regs
    const float iz = invz[r2];
    float* arow = attn_f + ((size_t)(b * N_ + n0 + r2)) * N_ + q2 * 8;
#pragma unroll
    for (int mt = 0; mt < 16; ++mt) {
        bf16x8 t8 = tr[mt];
        float4 f0 = make_float4((float)t8[0] * iz, (float)t8[1] * iz,
                                (float)t8[2] * iz, (float)t8[3] * iz);
        float4 f1 = make_float4((float)t8[4] * iz, (float)t8[5] * iz,
                                (float)t8[6] * iz, (float)t8[7] * iz);
        *(float4*)(arow + mt * 64)     = f0;
        *(float4*)(arow + mt * 64 + 4) = f1;
    }
}

// ---------------------------------------------------------------------------
// proj2: h2 = xc_bf16 @ (n0<512 ? W1o : W2o) via MFMA (K=256); ao-dots + h2t out.
__global__ __launch_bounds__(256) void proj2_kernel(
    const __bf16* __restrict__ xcb, const float* __restrict__ W1o,
    const float* __restrict__ W2o, const float* __restrict__ ao,
    __bf16* __restrict__ h2t, float* __restrict__ A1o, float* __restrict__ A2o)
{
    const int tile = blockIdx.x, b = blockIdx.y;
    const int n0 = tile * 64;
    const float* W = (n0 < 512) ? W1o : W2o;

    __shared__ __align__(16) __bf16 xs[64][264];
    __shared__ __align__(16) __bf16 Wt[64][264];
    __shared__ __align__(16) float as_[128];

    const int tid = threadIdx.x;
    if (tid < 128) as_[tid] = ao[tid];

#pragma unroll
    for (int i = 0; i < 8; ++i) {
        int idx = i * 256 + tid;
        int row = idx >> 5, c = (idx & 31) * 8;
        *(bf16x8*)&xs[row][c] =
            *(const bf16x8*)(xcb + ((size_t)(b * N_ + n0 + row)) * 256 + c);
    }
#pragma unroll
    for (int i = 0; i < 16; ++i) {
        int idx = i * 256 + tid;
        int k = idx >> 4, n4 = (idx & 15) * 4;
        float4 wv = *(const float4*)(W + (size_t)k * 64 + n4);
        Wt[n4 + 0][k] = (__bf16)wv.x;
        Wt[n4 + 1][k] = (__bf16)wv.y;
        Wt[n4 + 2][k] = (__bf16)wv.z;
        Wt[n4 + 3][k] = (__bf16)wv.w;
    }
    __syncthreads();

    const int w = tid >> 6, L = tid & 63, quad = L >> 4, lo = L & 15;
    floatx4 acc[4] = {{0,0,0,0},{0,0,0,0},{0,0,0,0},{0,0,0,0}};
#pragma unroll
    for (int kc = 0; kc < 8; ++kc) {
        bf16x8 af = *(bf16x8*)&xs[16 * w + lo][kc * 32 + quad * 8];
#pragma unroll
        for (int t = 0; t < 4; ++t) {
            bf16x8 bv = *(bf16x8*)&Wt[16 * t + lo][kc * 32 + quad * 8];
            acc[t] = mfma_bf16(af, bv, acc[t]);
        }
    }

    float p1[4] = {0, 0, 0, 0}, p2[4] = {0, 0, 0, 0};
#pragma unroll
    for (int t = 0; t < 4; ++t) {
        float a1w = as_[16 * t + lo], a2w = as_[64 + 16 * t + lo];
#pragma unroll
        for (int i = 0; i < 4; ++i) { p1[i] += acc[t][i] * a1w; p2[i] += acc[t][i] * a2w; }
    }
#pragma unroll
    for (int s = 1; s < 16; s <<= 1)
#pragma unroll
        for (int i = 0; i < 4; ++i) {
            p1[i] += __shfl_xor(p1[i], s);
            p2[i] += __shfl_xor(p2[i], s);
        }
    if (lo == 0) {
#pragma unroll
        for (int i = 0; i < 4; ++i) {
            int n = 16 * w + quad * 4 + i;
            A1o[b * N_ + n0 + n] = p1[i];
            A2o[b * N_ + n0 + n] = p2[i];
        }
    }

    __syncthreads();
#pragma unroll
    for (int t = 0; t < 4; ++t)
#pragma unroll
        for (int i = 0; i < 4; ++i)
            xs[16 * w + quad * 4 + i][16 * t + lo] = (__bf16)acc[t][i];
    __syncthreads();
    const int d = tid & 63, ch = tid >> 6;
    bf16x8 v0, v1;
#pragma unroll
    for (int j = 0; j < 8; ++j) v0[j] = xs[ch * 16 + j][d];
#pragma unroll
    for (int j = 0; j < 8; ++j) v1[j] = xs[ch * 16 + 8 + j][d];
    bf16x8* dst = (bf16x8*)(h2t + ((size_t)b * 64 + d) * N_ + n0 + ch * 16);
    dst[0] = v0; dst[1] = v1;
}

// ---------------------------------------------------------------------------
extern "C" void kernel_launch(void* const* d_in, const int* in_sizes, int n_in,
                              void* d_out, int out_size, void* d_ws, size_t ws_size,
                              hipStream_t stream)
{
    const float* x    = (const float*)d_in[0];
    const float* mask = (const float*)d_in[1];
    const float* W1   = (const float*)d_in[2];
    const float* W2   = (const float*)d_in[3];
    const float* a    = (const float*)d_in[4];
    const float* W1o  = (const float*)d_in[5];
    const float* W2o  = (const float*)d_in[6];
    const float* ao   = (const float*)d_in[7];

    float* out      = (float*)d_out;                 // [16,1024,64] fp32
    float* attn_out = out + (size_t)B_ * N_ * 64;    // [16,1024,1024] fp32

    float*    ws    = (float*)d_ws;
    float*    A1    = ws;                       // 65536 f
    float*    A2    = A1 + 65536;               // 65536 f
    float*    A1o   = A2 + 65536;               // 16384 f
    float*    A2o   = A1o + 16384;              // 16384 f
    __bf16*   h1t   = (__bf16*)(A2o + 16384);   // 4*16*64*1024 bf16
    __bf16*   h2t   = h1t + 4194304;            // 16*64*1024 bf16
    __bf16*   xcb   = h2t + 1048576;            // 16*1024*256 bf16
    unsigned* bitsG = (unsigned*)(xcb + 4194304); // 32768 u32

    maskbits_kernel<<<dim3(128), 256, 0, stream>>>(mask, bitsG);
    proj1_kernel<<<dim3(16, 16, 4), 256, 0, stream>>>(x, W1, W2, a, h1t, A1, A2);
    attn1_kernel<<<dim3(16, 4, 16), 256, 0, stream>>>(A1, A2, h1t, bitsG, xcb);
    proj2_kernel<<<dim3(16, 16, 1), 256, 0, stream>>>(xcb, W1o, W2o, ao, h2t, A1o, A2o);
    attn2_kernel<<<dim3(16, 1, 32), 256, 0, stream>>>(A1o, A2o, h2t, bitsG, out, attn_out);
}